// Round 10
// baseline (459.844 us; speedup 1.0000x reference)
//
#include <hip/hip_runtime.h>
#include <math.h>

#define N_NODES 50000
#define N_EDGES 800000
#define ETOT    (N_EDGES + N_NODES)   // 850000, with self loops
// col array: padded rows (each row padded to multiple of 4) + 64-int tail
#define COL_CAP (ETOT + 3 * N_NODES + 64)

typedef short bf16x8 __attribute__((ext_vector_type(8)));
typedef float f32x4  __attribute__((ext_vector_type(4)));
typedef float f32x2  __attribute__((ext_vector_type(2)));

__device__ __forceinline__ float b2f(unsigned int u16) {   // low 16 bits hold bf16
    return __uint_as_float(u16 << 16);
}
__device__ __forceinline__ unsigned short f2b(float f) {   // RNE
    unsigned int u = __float_as_uint(f);
    u += 0x7fffu + ((u >> 16) & 1u);
    return (unsigned short)(u >> 16);
}

// ---------------------------------------------------------------------------
// Prep: zero deg+flag, cast W1/W2/W3 fp32->bf16, cast x fp32->bf16,
// and (blocks 0..7) build U[16][128]: rows 0..7 = W1_h^T a1_src_h,
// rows 8..15 = W1_h^T a1_dst_h (fp32).
// ---------------------------------------------------------------------------
__global__ __launch_bounds__(256) void k_prep(const float* __restrict__ x,
                                              const float* __restrict__ w1,
                                              const float* __restrict__ w2,
                                              const float* __restrict__ w3,
                                              const float* __restrict__ a1s,
                                              const float* __restrict__ a1d,
                                              unsigned short* __restrict__ xb,
                                              unsigned short* __restrict__ o1,
                                              unsigned short* __restrict__ o2,
                                              unsigned short* __restrict__ o3,
                                              float* __restrict__ U,
                                              int* __restrict__ deg,
                                              int* __restrict__ flag) {
    int i = blockIdx.x * 256 + threadIdx.x;
    if (i < N_NODES) deg[i] = 0;
    if (i == 0) *flag = 0;
    if (blockIdx.x < 8) {
        int h = blockIdx.x;
        int which = threadIdx.x >> 7, k = threadIdx.x & 127;
        const float* av = which ? a1d : a1s;
        float acc = 0.f;
        for (int c = 0; c < 64; ++c)
            acc += av[h * 64 + c] * w1[(size_t)(h * 64 + c) * 128 + k];
        U[(which * 8 + h) * 128 + k] = acc;
    }
    if (i < 512 * 128 / 4) {
        float4 v = ((const float4*)w1)[i];
        ushort2* o = (ushort2*)(o1 + i * 4);
        o[0] = make_ushort2(f2b(v.x), f2b(v.y));
        o[1] = make_ushort2(f2b(v.z), f2b(v.w));
    }
    if (i < 64 * 512 / 4) {
        float4 v = ((const float4*)w2)[i];
        ushort2* o = (ushort2*)(o2 + i * 4);
        o[0] = make_ushort2(f2b(v.x), f2b(v.y));
        o[1] = make_ushort2(f2b(v.z), f2b(v.w));
    }
    if (i < 64 * 64 / 4) {
        float4 v = ((const float4*)w3)[i];
        ushort2* o = (ushort2*)(o3 + i * 4);
        o[0] = make_ushort2(f2b(v.x), f2b(v.y));
        o[1] = make_ushort2(f2b(v.z), f2b(v.w));
    }
    if (i < N_NODES * 128 / 8) {
        const float4* xp = (const float4*)x + (size_t)i * 2;
        float4 v0 = xp[0], v1 = xp[1];
        unsigned int u0 = (unsigned int)f2b(v0.x) | ((unsigned int)f2b(v0.y) << 16);
        unsigned int u1 = (unsigned int)f2b(v0.z) | ((unsigned int)f2b(v0.w) << 16);
        unsigned int u2 = (unsigned int)f2b(v1.x) | ((unsigned int)f2b(v1.y) << 16);
        unsigned int u3 = (unsigned int)f2b(v1.z) | ((unsigned int)f2b(v1.w) << 16);
        *(uint4*)(xb + (size_t)i * 8) = make_uint4(u0, u1, u2, u3);
    }
}

// ---------------------------------------------------------------------------
// Attention logits from input space: asrc/adst[N,8] = xb[N,128] . U
// ---------------------------------------------------------------------------
__global__ __launch_bounds__(256) void k_attn(const unsigned short* __restrict__ xb,
                                              const float* __restrict__ U,
                                              float* __restrict__ asrc,
                                              float* __restrict__ adst) {
    __shared__ float sU[16 * 132];           // stride 132 floats
    __shared__ unsigned short sX[16 * 136];  // stride 136 shorts (16B-aligned rows)
    int t = threadIdx.x;
    for (int i = t; i < 2048; i += 256) sU[(i >> 7) * 132 + (i & 127)] = U[i];
    int n0 = blockIdx.x * 16;
    {
        int r = t >> 4, c = (t & 15) * 8;
        *(uint4*)&sX[r * 136 + c] = *(const uint4*)(xb + (size_t)(n0 + r) * 128 + c);
    }
    __syncthreads();
    int nl = t >> 4, o = t & 15;
    const unsigned short* xr = sX + nl * 136;
    const float* ur = sU + o * 132;
    float acc = 0.f;
#pragma unroll 8
    for (int k2 = 0; k2 < 128; ++k2) acc += b2f(xr[k2]) * ur[k2];
    int n = n0 + nl;
    if (o < 8) asrc[n * 8 + o] = acc;
    else       adst[n * 8 + (o - 8)] = acc;
}

// ---------------------------------------------------------------------------
// Edge-index dtype detection (reference int64 vs harness int32).
// ---------------------------------------------------------------------------
__global__ void k_detect(const int* __restrict__ idx, int* __restrict__ flag) {
    int i = blockIdx.x * blockDim.x + threadIdx.x;   // 8192 threads
    int v = idx[2 * i + 1];
    unsigned long long any = __ballot(v != 0);
    if ((threadIdx.x & 63) == 0 && any) atomicOr(flag, 1);   // 1 => int32 data
}

__device__ __forceinline__ int edge_src(const int* idx, int e, int is32) {
    return is32 ? idx[e] : idx[2 * e];
}
__device__ __forceinline__ int edge_dst(const int* idx, int e, int is32) {
    return is32 ? idx[N_EDGES + e] : idx[2 * (N_EDGES + e)];
}

// ---------------------------------------------------------------------------
// CSR build: degree -> 3-kernel scan (PADDED row starts) -> scatter
// ---------------------------------------------------------------------------
__global__ void k_degree(const int* __restrict__ idx, const int* __restrict__ flag,
                         int* __restrict__ deg) {
    int e = blockIdx.x * blockDim.x + threadIdx.x;
    if (e >= ETOT) return;
    int is32 = *flag;
    int d = (e < N_EDGES) ? edge_dst(idx, e, is32) : (e - N_EDGES);
    atomicAdd(&deg[d], 1);
}

__global__ __launch_bounds__(256) void k_scan1(const int* __restrict__ deg,
                                               int* __restrict__ rowptr,
                                               int* __restrict__ bsum) {
    __shared__ int sd[256];
    int t = threadIdx.x;
    int i = blockIdx.x * 256 + t;
    int v = (i < N_NODES) ? ((deg[i] + 3) & ~3) : 0;   // padded degree
    sd[t] = v;
    __syncthreads();
#pragma unroll
    for (int off = 1; off < 256; off <<= 1) {
        int a = (t >= off) ? sd[t - off] : 0;
        __syncthreads();
        sd[t] += a;
        __syncthreads();
    }
    if (i < N_NODES) rowptr[i] = sd[t] - v;
    if (t == 255) bsum[blockIdx.x] = sd[255];
}

__global__ __launch_bounds__(256) void k_scan2(int* __restrict__ bsum,
                                               int* __restrict__ boff,
                                               int* __restrict__ rowptr,
                                               int nb) {
    __shared__ int sd[256];
    int t = threadIdx.x;
    int v = (t < nb) ? bsum[t] : 0;
    sd[t] = v;
    __syncthreads();
#pragma unroll
    for (int off = 1; off < 256; off <<= 1) {
        int a = (t >= off) ? sd[t - off] : 0;
        __syncthreads();
        sd[t] += a;
        __syncthreads();
    }
    boff[t] = sd[t] - v;
    if (t == 255) rowptr[N_NODES] = sd[255];    // total padded length
}

__global__ __launch_bounds__(256) void k_scan3(int* __restrict__ rowptr,
                                               const int* __restrict__ boff,
                                               const int* __restrict__ deg,
                                               int* __restrict__ cursor,
                                               int* __restrict__ col) {
    int i = blockIdx.x * 256 + threadIdx.x;
    if (i == 0) {                                // zero 48-int tail pad
        int tot = rowptr[N_NODES];
        for (int q = 0; q < 48; ++q) col[tot + q] = 0;
    }
    if (i >= N_NODES) return;
    int r = rowptr[i] + boff[blockIdx.x];
    rowptr[i] = r;
    cursor[i] = r;
    int d = deg[i];
    int pd = (d + 3) & ~3;
    for (int p = r + d; p < r + pd; ++p) col[p] = 0;   // zero row pads
}

__global__ void k_scatter(const int* __restrict__ idx, const int* __restrict__ flag,
                          int* __restrict__ cursor, int* __restrict__ col) {
    int e = blockIdx.x * blockDim.x + threadIdx.x;
    if (e >= ETOT) return;
    int is32 = *flag;
    int s, d;
    if (e < N_EDGES) { s = edge_src(idx, e, is32); d = edge_dst(idx, e, is32); }
    else             { s = d = e - N_EDGES; }
    int pos = atomicAdd(&cursor[d], 1);
    col[pos] = s;
}

// ---------------------------------------------------------------------------
// Layer-1 aggregation in INPUT space (R3's proven VALU version, 256B/edge).
// NO LDS, no barriers — max occupancy for the latency-bound gather loop.
// ---------------------------------------------------------------------------
__device__ __forceinline__ void aggx_slot(int idx, int rem, float tt, unsigned int xx,
                                          float adn, float& ssum, f32x2* acc) {
    float e = tt + adn;
    e = fmaxf(e, 0.2f * e);
    float ex = __expf(e);
    ex = (idx < rem) ? ex : 0.f;
    ssum += ex;
    float fx = __uint_as_float(xx << 16);
    float fy = __uint_as_float(xx & 0xffff0000u);
    int exi = __float_as_int(ex);
#pragma unroll
    for (int hh = 0; hh < 8; ++hh) {
        float wh = __int_as_float(__builtin_amdgcn_readlane(exi, hh << 3));
        acc[hh].x = fmaf(fx, wh, acc[hh].x);
        acc[hh].y = fmaf(fy, wh, acc[hh].y);
    }
}

__global__ __launch_bounds__(256) void k_aggx(const unsigned short* __restrict__ xb,  // [N,128]
                                              const float* __restrict__ asrc,         // [N,8]
                                              const float* __restrict__ adst,         // [N,8]
                                              const int* __restrict__ rowptr,         // padded starts
                                              const int* __restrict__ degv,
                                              const int* __restrict__ col,
                                              unsigned short* __restrict__ aggX) {    // [N,1024]
    int n = blockIdx.x * 4 + (threadIdx.x >> 6);
    if (n >= N_NODES) return;
    int l = threadIdx.x & 63;
    int j = l >> 3;
    unsigned lx2 = (unsigned)(l << 1);
    int start = rowptr[n];
    int end   = start + degv[n];
    float adn = adst[((unsigned)n << 3) + (unsigned)j];

    float ssum = 0.f;
    f32x2 acc[8];
#pragma unroll
    for (int hh = 0; hh < 8; ++hh) acc[hh] = (f32x2){0.f, 0.f};

    float tA0, tA1, tA2, tA3, tB0, tB1, tB2, tB3;
    unsigned int xA0, xA1, xA2, xA3, xB0, xB1, xB2, xB3;
    int4 cA, cB;

#define GATHX(c, T0, T1, T2, T3, X0, X1, X2, X3)                              \
    T0 = asrc[(((unsigned)(c).x) << 3) + (unsigned)j];                        \
    T1 = asrc[(((unsigned)(c).y) << 3) + (unsigned)j];                        \
    T2 = asrc[(((unsigned)(c).z) << 3) + (unsigned)j];                        \
    T3 = asrc[(((unsigned)(c).w) << 3) + (unsigned)j];                        \
    X0 = *(const unsigned int*)(xb + (((unsigned)(c).x) << 7) + lx2);         \
    X1 = *(const unsigned int*)(xb + (((unsigned)(c).y) << 7) + lx2);         \
    X2 = *(const unsigned int*)(xb + (((unsigned)(c).z) << 7) + lx2);         \
    X3 = *(const unsigned int*)(xb + (((unsigned)(c).w) << 7) + lx2);

    int k = start;
    cA = *(const int4*)(col + k);
    cB = *(const int4*)(col + k + 4);
    GATHX(cA, tA0, tA1, tA2, tA3, xA0, xA1, xA2, xA3);
    for (;;) {
        bool hasB = (k + 4 < end);
        if (hasB) {
            GATHX(cB, tB0, tB1, tB2, tB3, xB0, xB1, xB2, xB3);
            cA = *(const int4*)(col + k + 8);
        }
        {
            int rem = end - k;
            aggx_slot(0, rem, tA0, xA0, adn, ssum, acc);
            aggx_slot(1, rem, tA1, xA1, adn, ssum, acc);
            aggx_slot(2, rem, tA2, xA2, adn, ssum, acc);
            aggx_slot(3, rem, tA3, xA3, adn, ssum, acc);
        }
        k += 4;
        if (!hasB) break;
        bool hasA = (k + 4 < end);
        if (hasA) {
            GATHX(cA, tA0, tA1, tA2, tA3, xA0, xA1, xA2, xA3);
            cB = *(const int4*)(col + k + 8);
        }
        {
            int rem = end - k;
            aggx_slot(0, rem, tB0, xB0, adn, ssum, acc);
            aggx_slot(1, rem, tB1, xB1, adn, ssum, acc);
            aggx_slot(2, rem, tB2, xB2, adn, ssum, acc);
            aggx_slot(3, rem, tB3, xB3, adn, ssum, acc);
        }
        k += 4;
        if (!hasA) break;
    }
#undef GATHX

    // normalize and store: per head, wave writes 256B contiguous
    size_t base = (size_t)n * 1024 + lx2;
#pragma unroll
    for (int hh = 0; hh < 8; ++hh) {
        float sh = __int_as_float(__builtin_amdgcn_readlane(__float_as_int(ssum), hh << 3));
        float iv = 1.f / (sh + 1e-16f);
        unsigned int lo = f2b(acc[hh].x * iv);
        unsigned int hi = f2b(acc[hh].y * iv);
        *(unsigned int*)(aggX + base + hh * 128) = lo | (hi << 16);
    }
}

// ---------------------------------------------------------------------------
// FUSED GEMM1+GEMM2, v3: 32-row tiles, 512 threads (8 waves), ONE barrier.
// Halved LDS (33.3KB + red) -> 4 blocks/CU (32 waves) for latency hiding.
// Stage 1: wave w == head w. 32x64 head tile (32 MFMAs), A read directly
//   from global aggX, B from L2-hot W1. ELU -> X2s[32][520].
// Stage 2: 8 waves x one 16x16 tile (rt2 = w&1, ct2 = w>>2? no: ct2 = w>>1),
//   K=512 from LDS, W2 from global; split attention epilogue combines the
//   4 waves per row-tile via LDS.
// ---------------------------------------------------------------------------
__global__ __launch_bounds__(512, 8) void k_gemm12(const unsigned short* __restrict__ aggX, // [N,1024]
                                                   const unsigned short* __restrict__ W1b,  // [512,128]
                                                   const float* __restrict__ b1,            // [512]
                                                   const unsigned short* __restrict__ W2b,  // [64,512]
                                                   const float* __restrict__ a2s,           // [64]
                                                   const float* __restrict__ a2d,           // [64]
                                                   unsigned short* __restrict__ h2,         // [N,64]
                                                   float* __restrict__ asb,                 // [N]
                                                   float* __restrict__ adb) {               // [N]
    __shared__ unsigned short X2s[32 * 520];   // 33280 B
    __shared__ float red_s[8][16];
    __shared__ float red_d[8][16];
    int t = threadIdx.x;
    int w = t >> 6, l = t & 63;
    int quad = l >> 4, lm = l & 15;
    int m0 = blockIdx.x * 32;

    // ---- stage 1: wave w computes head w's 32x64 tile, barrier-free ----
    {
        int h = w;
        f32x4 acc1[2][4];    // [row-tile][col-tile]
#pragma unroll
        for (int rt = 0; rt < 2; ++rt)
#pragma unroll
            for (int ct = 0; ct < 4; ++ct) acc1[rt][ct] = (f32x4){0.f, 0.f, 0.f, 0.f};

#pragma unroll
        for (int k0 = 0; k0 < 4; ++k0) {                 // K = 128, 4 steps of 32
            bf16x8 af[2];
#pragma unroll
            for (int rt = 0; rt < 2; ++rt) {
                int m = m0 + rt * 16 + lm;
                uint4 au = make_uint4(0, 0, 0, 0);
                if (m < N_NODES)
                    au = *(const uint4*)(aggX + (size_t)m * 1024 + h * 128 + k0 * 32 + quad * 8);
                af[rt] = *(bf16x8*)&au;
            }
#pragma unroll
            for (int ct = 0; ct < 4; ++ct) {
                uint4 bu = *(const uint4*)(W1b + (size_t)(h * 64 + ct * 16 + lm) * 128 + k0 * 32 + quad * 8);
                bf16x8 bf_ = *(bf16x8*)&bu;
#pragma unroll
                for (int rt = 0; rt < 2; ++rt)
                    acc1[rt][ct] = __builtin_amdgcn_mfma_f32_16x16x32_bf16(af[rt], bf_, acc1[rt][ct], 0, 0, 0);
            }
        }
        // bias + ELU -> X2s slab (cols h*64 .. h*64+63)
#pragma unroll
        for (int ct = 0; ct < 4; ++ct) {
            float bcol = b1[h * 64 + ct * 16 + lm];
#pragma unroll
            for (int rt = 0; rt < 2; ++rt)
#pragma unroll
                for (int g = 0; g < 4; ++g) {
                    float v = acc1[rt][ct][g] + bcol;
                    v = (v > 0.f) ? v : expm1f(v);
                    X2s[(rt * 16 + quad * 4 + g) * 520 + h * 64 + ct * 16 + lm] = f2b(v);
                }
        }
    }
    __syncthreads();

    // ---- stage 2: wave w computes 16x16 tile (rt2 = w&1, ct2 = w>>1) ----
    int rt2 = w & 1;
    int ct2 = w >> 1;          // 0..3
    f32x4 acc2 = (f32x4){0.f, 0.f, 0.f, 0.f};
#pragma unroll 4
    for (int k0 = 0; k0 < 512; k0 += 32) {
        bf16x8 af = *(const bf16x8*)&X2s[(rt2 * 16 + lm) * 520 + k0 + quad * 8];
        uint4 bu = *(const uint4*)(W2b + (size_t)(ct2 * 16 + lm) * 512 + k0 + quad * 8);
        acc2 = __builtin_amdgcn_mfma_f32_16x16x32_bf16(af, *(bf16x8*)&bu, acc2, 0, 0, 0);
    }

    // h2 store (bf16)
#pragma unroll
    for (int g = 0; g < 4; ++g) {
        int m = m0 + rt2 * 16 + quad * 4 + g;
        if (m < N_NODES) h2[(size_t)m * 64 + ct2 * 16 + lm] = f2b(acc2[g]);
    }

    // layer-2 attention-coefficient epilogue (fp32 accumulators)
    {
        float as = a2s[ct2 * 16 + lm], ad = a2d[ct2 * 16 + lm];
#pragma unroll
        for (int g = 0; g < 4; ++g) {
            float vs = acc2[g] * as;
            float vd = acc2[g] * ad;
#pragma unroll
            for (int off = 1; off < 16; off <<= 1) {
                vs += __shfl_xor(vs, off);
                vd += __shfl_xor(vd, off);
            }
            if (lm == 0) {
                red_s[w][quad * 4 + g] = vs;
                red_d[w][quad * 4 + g] = vd;
            }
        }
    }
    __syncthreads();
    if (t < 32) {
        int rt = t >> 4, rr = t & 15;
        float vs = red_s[rt][rr] + red_s[rt + 2][rr] + red_s[rt + 4][rr] + red_s[rt + 6][rr];
        float vd = red_d[rt][rr] + red_d[rt + 2][rr] + red_d[rt + 4][rr] + red_d[rt + 6][rr];
        int m = m0 + t;
        if (m < N_NODES) {
            asb[m] = vs;
            adb[m] = vd;
        }
    }
}

// ---------------------------------------------------------------------------
// bf16 MFMA GEMM: C[M,64] = A[M,K] @ W[64,K]^T. 64x64 tile, 4 waves.
// bf16 C store + attention-coefficient epilogue (layer 3).
// ---------------------------------------------------------------------------
__global__ __launch_bounds__(256) void k_gemm(const unsigned short* __restrict__ Ab,
                                              const unsigned short* __restrict__ W,
                                              unsigned short* __restrict__ C,
                                              const float* __restrict__ a_src,
                                              const float* __restrict__ a_dst,
                                              float* __restrict__ asb,
                                              float* __restrict__ adb,
                                              int M, int K, int Nout) {
    __shared__ unsigned short As[64 * 40];   // row stride 40 shorts (80 B)
    __shared__ unsigned short Bs[64 * 40];
    __shared__ float red_s[4][64];
    __shared__ float red_d[4][64];
    int t = threadIdx.x;
    int w = t >> 6, l = t & 63;
    int quad = l >> 4, lm = l & 15;
    int m0 = blockIdx.y * 64, n0 = blockIdx.x * 64;
    int lr = t >> 2;
    int lc = (t & 3) * 8;

    f32x4 acc[4];
#pragma unroll
    for (int r = 0; r < 4; ++r) acc[r] = (f32x4){0.f, 0.f, 0.f, 0.f};

    for (int k0 = 0; k0 < K; k0 += 32) {
        int m = m0 + lr;
        uint4 av = make_uint4(0, 0, 0, 0);
        if (m < M) av = *(const uint4*)(Ab + (size_t)m * K + k0 + lc);
        *(uint4*)&As[lr * 40 + lc] = av;
        uint4 bv = *(const uint4*)(W + (size_t)(n0 + lr) * K + k0 + lc);
        *(uint4*)&Bs[lr * 40 + lc] = bv;
        __syncthreads();

        bf16x8 bfrag = *(const bf16x8*)&Bs[(w * 16 + lm) * 40 + quad * 8];
#pragma unroll
        for (int r = 0; r < 4; ++r) {
            bf16x8 afrag = *(const bf16x8*)&As[(r * 16 + lm) * 40 + quad * 8];
            acc[r] = __builtin_amdgcn_mfma_f32_16x16x32_bf16(afrag, bfrag, acc[r], 0, 0, 0);
        }
        __syncthreads();
    }

    // C store (bf16)
#pragma unroll
    for (int r = 0; r < 4; ++r)
#pragma unroll
        for (int g = 0; g < 4; ++g) {
            int m = m0 + r * 16 + quad * 4 + g;
            if (m < M) C[(size_t)m * Nout + n0 + w * 16 + lm] = f2b(acc[r][g]);
        }

    // Attention-coefficient epilogue (fp32 accumulators)
    float as = a_src[w * 16 + lm];
    float ad = a_dst[w * 16 + lm];
#pragma unroll
    for (int r = 0; r < 4; ++r) {
#pragma unroll
        for (int g = 0; g < 4; ++g) {
            float vs = acc[r][g] * as;
            float vd = acc[r][g] * ad;
#pragma unroll
            for (int off = 1; off < 16; off <<= 1) {
                vs += __shfl_xor(vs, off);
                vd += __shfl_xor(vd, off);
            }
            if (lm == 0) {
                red_s[w][r * 16 + quad * 4 + g] = vs;
                red_d[w][r * 16 + quad * 4 + g] = vd;
            }
        }
    }
    __syncthreads();
    if (t < 64) {
        float vs = red_s[0][t] + red_s[1][t] + red_s[2][t] + red_s[3][t];
        float vd = red_d[0][t] + red_d[1][t] + red_d[2][t] + red_d[3][t];
        int m = m0 + t;
        if (m < M) {
            asb[m] = vs;
            adb[m] = vd;
        }
    }
}

// ---------------------------------------------------------------------------
// Fused segment-softmax + aggregation, H=1, C=64 (layers 2,3), bf16 h.
// v2: 4 edges per wave-step. Lane l = (group g = l>>4, chan-quad i = l&15).
// Group g handles edge-slot g of each padded 4-chunk; lane loads ushort4
// (channels 4i..4i+3, 8B). Same 128B/edge traffic, 4x fewer in-order steps
// per node. Cross-group shfl_xor(16/32) reduce; group 0 writes.
// ---------------------------------------------------------------------------
__global__ __launch_bounds__(256) void k_agg1(const unsigned short* __restrict__ h, // [N,64]
                                              const float* __restrict__ asrc,       // [N]
                                              const float* __restrict__ adst,       // [N]
                                              const int* __restrict__ rowptr,       // padded starts
                                              const int* __restrict__ degv,
                                              const int* __restrict__ col,
                                              const float* __restrict__ bias,       // [64]
                                              unsigned short* __restrict__ out) {   // [N,64]
    int n = blockIdx.x * 4 + (threadIdx.x >> 6);
    if (n >= N_NODES) return;
    int l = threadIdx.x & 63;
    int g = l >> 4;                    // edge-slot group 0..3
    int i = l & 15;                    // channel-quad index
    unsigned ci = (unsigned)(i << 2);  // channel base 4i
    int start = rowptr[n];
    int end   = start + degv[n];
    float adn = adst[n];

    float ssum = 0.f;
    f32x4 o4 = (f32x4){0.f, 0.f, 0.f, 0.f};

    int sA, sB;
    float tA, tB;
    ushort4 hA, hB;

#define AGG1_ACC(TT, HH, rem)                                                 \
    {                                                                         \
        float e = TT + adn;                                                   \
        e = fmaxf(e, 0.2f * e);                                               \
        float ex = __expf(e);                                                 \
        ex = (g < (rem)) ? ex : 0.f;                                          \
        ssum += ex;                                                           \
        o4[0] = fmaf(ex, b2f((HH).x), o4[0]);                                 \
        o4[1] = fmaf(ex, b2f((HH).y), o4[1]);                                 \
        o4[2] = fmaf(ex, b2f((HH).z), o4[2]);                                 \
        o4[3] = fmaf(ex, b2f((HH).w), o4[3]);                                 \
    }

    int k = start;
    sA = col[k + g];
    tA = asrc[sA];
    hA = *(const ushort4*)(h + (((unsigned)sA) << 6) + ci);
    for (;;) {
        bool hasB = (k + 4 < end);
        if (hasB) {
            sB = col[k + 4 + g];
            tB = asrc[sB];
            hB = *(const ushort4*)(h + (((unsigned)sB) << 6) + ci);
        }
        AGG1_ACC(tA, hA, end - k);
        k += 4;
        if (!hasB) break;
        bool hasA = (k + 4 < end);
        if (hasA) {
            sA = col[k + 4 + g];
            tA = asrc[sA];
            hA = *(const ushort4*)(h + (((unsigned)sA) << 6) + ci);
        }
        AGG1_ACC(tB, hB, end - k);
        k += 4;
        if (!hasA) break;
    }
#undef AGG1_ACC

    // combine the 4 edge-slot groups
    ssum += __shfl_xor(ssum, 16);
    ssum += __shfl_xor(ssum, 32);
#pragma unroll
    for (int c = 0; c < 4; ++c) {
        o4[c] += __shfl_xor(o4[c], 16);
        o4[c] += __shfl_xor(o4[c], 32);
    }

    if (g == 0) {
        float inv = 1.f / (ssum + 1e-16f);
        float4 bv = *(const float4*)(bias + ci);
        float v0 = o4[0] * inv + bv.x; v0 = (v0 > 0.f) ? v0 : expm1f(v0);
        float v1 = o4[1] * inv + bv.y; v1 = (v1 > 0.f) ? v1 : expm1f(v1);
        float v2 = o4[2] * inv + bv.z; v2 = (v2 > 0.f) ? v2 : expm1f(v2);
        float v3 = o4[3] * inv + bv.w; v3 = (v3 > 0.f) ? v3 : expm1f(v3);
        ushort4 ov = make_ushort4(f2b(v0), f2b(v1), f2b(v2), f2b(v3));
        *(ushort4*)(out + (size_t)n * 64 + ci) = ov;
    }
}

// ---------------------------------------------------------------------------
// Classifier: out[N,10] = h[N,64](bf16) @ Wc[10,64]^T + bc, fp32 out.
// ---------------------------------------------------------------------------
__global__ __launch_bounds__(256) void k_classifier(const unsigned short* __restrict__ h,
                                                    const float* __restrict__ Wc,
                                                    const float* __restrict__ bc,
                                                    float* __restrict__ out) {
    __shared__ float sW[640];
    for (int i = threadIdx.x; i < 640; i += blockDim.x) sW[i] = Wc[i];
    __syncthreads();
    int idx = blockIdx.x * blockDim.x + threadIdx.x;
    if (idx >= N_NODES * 10) return;
    int n = idx / 10, d = idx - n * 10;
    const unsigned short* hr = h + (size_t)n * 64;
    const float* wr = sW + d * 64;
    float acc = 0.f;
#pragma unroll
    for (int c = 0; c < 64; ++c) acc += b2f(hr[c]) * wr[c];
    out[idx] = acc + bc[d];
}

// ---------------------------------------------------------------------------
extern "C" void kernel_launch(void* const* d_in, const int* in_sizes, int n_in,
                              void* d_out, int out_size, void* d_ws, size_t ws_size,
                              hipStream_t stream) {
    const float* x    = (const float*)d_in[0];
    const int*   eidx = (const int*)  d_in[1];
    const float* W1   = (const float*)d_in[2];
    const float* a1s  = (const float*)d_in[3];
    const float* a1d  = (const float*)d_in[4];
    const float* b1   = (const float*)d_in[5];
    const float* W2   = (const float*)d_in[6];
    const float* a2s  = (const float*)d_in[7];
    const float* a2d  = (const float*)d_in[8];
    const float* b2   = (const float*)d_in[9];
    const float* W3   = (const float*)d_in[10];
    const float* a3s  = (const float*)d_in[11];
    const float* a3d  = (const float*)d_in[12];
    const float* b3   = (const float*)d_in[13];
    const float* Wc   = (const float*)d_in[14];
    const float* bc   = (const float*)d_in[15];
    float* out = (float*)d_out;

    // Workspace layout
    float* asbuf = (float*)d_ws;                              // N*8 fp32
    float* adbuf = asbuf + (size_t)N_NODES * 8;               // N*8 fp32
    unsigned short* aggX = (unsigned short*)(adbuf + (size_t)N_NODES * 8); // N*1024
    unsigned short* h2  = aggX + (size_t)N_NODES * 1024;      // N*64
    unsigned short* x3  = h2  + (size_t)N_NODES * 64;         // N*64
    unsigned short* h3  = x3  + (size_t)N_NODES * 64;         // N*64
    unsigned short* x4  = h3  + (size_t)N_NODES * 64;         // N*64
    unsigned short* xb  = x4  + (size_t)N_NODES * 64;         // N*128 (bf16 x)
    unsigned short* W1b = xb  + (size_t)N_NODES * 128;        // 512*128
    unsigned short* W2b = W1b + 512 * 128;                    // 64*512
    unsigned short* W3b = W2b + 64 * 512;                     // 64*64
    float* U    = (float*)(W3b + 64 * 64);                    // 16*128 fp32
    int* ibase  = (int*)(U + 16 * 128);
    int* deg    = ibase;                                      // N (zeroed in k_prep)
    int* flag   = deg + N_NODES;                              // 1
    int* rowptr = flag + 1;                                   // N+1 (padded starts)
    int* cursor = rowptr + N_NODES + 1;                       // N
    int* bsum   = cursor + N_NODES;                           // 256
    int* boff   = bsum + 256;                                 // 256
    int* col    = boff + 256;                                 // COL_CAP

    dim3 blk(256);
    const int SCAN_BLOCKS = (N_NODES + 255) / 256;            // 196
    const int PREP_BLOCKS = (N_NODES * 128 / 8 + 255) / 256;  // 3125

    // Prep: casts + U + attention logits (independent of CSR)
    k_prep<<<PREP_BLOCKS, blk, 0, stream>>>(x, W1, W2, W3, a1s, a1d,
                                            xb, W1b, W2b, W3b, U, deg, flag);
    k_attn<<<N_NODES / 16, blk, 0, stream>>>(xb, U, asbuf, adbuf);

    // CSR build
    k_detect<<<32, blk, 0, stream>>>(eidx, flag);
    k_degree<<<(ETOT + 255) / 256, blk, 0, stream>>>(eidx, flag, deg);
    k_scan1<<<SCAN_BLOCKS, blk, 0, stream>>>(deg, rowptr, bsum);
    k_scan2<<<1, blk, 0, stream>>>(bsum, boff, rowptr, SCAN_BLOCKS);
    k_scan3<<<SCAN_BLOCKS, blk, 0, stream>>>(rowptr, boff, deg, cursor, col);
    k_scatter<<<(ETOT + 255) / 256, blk, 0, stream>>>(eidx, flag, cursor, col);

    int mblocks   = (N_NODES + 63) / 64;   // 782
    int m32blocks = (N_NODES + 31) / 32;   // 1563
    int nblocks   = N_NODES / 4;           // 12500 (exact)

    // Layer 1 agg (VALU, input space) -> aggX
    k_aggx<<<nblocks, blk, 0, stream>>>(xb, asbuf, adbuf, rowptr, deg, col, aggX);

    // Fused GEMM1+GEMM2 (v3: 32-row tiles, 8 waves, 1 barrier)
    k_gemm12<<<m32blocks, dim3(512), 0, stream>>>(aggX, W1b, b1, W2b, a2s, a2d,
                                                  h2, asbuf, adbuf);

    // Layer 2 agg: h2 -> x3
    k_agg1<<<nblocks, blk, 0, stream>>>(h2, asbuf, adbuf, rowptr, deg, col, b2, x3);

    // Layer 3: x3[N,64] -> h3[N,64] (+ attn coefs); agg -> x4
    k_gemm<<<dim3(1, mblocks), blk, 0, stream>>>(x3, W3b, h3,
                                                 a3s, a3d, asbuf, adbuf,
                                                 N_NODES, 64, 64);
    k_agg1<<<nblocks, blk, 0, stream>>>(h3, asbuf, adbuf, rowptr, deg, col, b3, x4);

    // Classifier
    k_classifier<<<(N_NODES * 10 + 255) / 256, blk, 0, stream>>>(x4, Wc, bc, out);
}

// Round 11
// 443.552 us; speedup vs baseline: 1.0367x; 1.0367x over previous
//
#include <hip/hip_runtime.h>
#include <math.h>

#define N_NODES 50000
#define N_EDGES 800000
#define ETOT    (N_EDGES + N_NODES)   // 850000, with self loops
// col array: padded rows (each row padded to multiple of 4) + 64-int tail
#define COL_CAP (ETOT + 3 * N_NODES + 64)

typedef short bf16x8 __attribute__((ext_vector_type(8)));
typedef float f32x4  __attribute__((ext_vector_type(4)));
typedef float f32x2  __attribute__((ext_vector_type(2)));

__device__ __forceinline__ float b2f(unsigned int u16) {   // low 16 bits hold bf16
    return __uint_as_float(u16 << 16);
}
__device__ __forceinline__ unsigned short f2b(float f) {   // RNE
    unsigned int u = __float_as_uint(f);
    u += 0x7fffu + ((u >> 16) & 1u);
    return (unsigned short)(u >> 16);
}

// ---------------------------------------------------------------------------
// Prep: zero deg+flag, cast W1/W2/W3 fp32->bf16, cast x fp32->bf16,
// and (blocks 0..7) build U[16][128]: rows 0..7 = W1_h^T a1_src_h,
// rows 8..15 = W1_h^T a1_dst_h (fp32).
// ---------------------------------------------------------------------------
__global__ __launch_bounds__(256) void k_prep(const float* __restrict__ x,
                                              const float* __restrict__ w1,
                                              const float* __restrict__ w2,
                                              const float* __restrict__ w3,
                                              const float* __restrict__ a1s,
                                              const float* __restrict__ a1d,
                                              unsigned short* __restrict__ xb,
                                              unsigned short* __restrict__ o1,
                                              unsigned short* __restrict__ o2,
                                              unsigned short* __restrict__ o3,
                                              float* __restrict__ U,
                                              int* __restrict__ deg,
                                              int* __restrict__ flag) {
    int i = blockIdx.x * 256 + threadIdx.x;
    if (i < N_NODES) deg[i] = 0;
    if (i == 0) *flag = 0;
    if (blockIdx.x < 8) {
        int h = blockIdx.x;
        int which = threadIdx.x >> 7, k = threadIdx.x & 127;
        const float* av = which ? a1d : a1s;
        float acc = 0.f;
        for (int c = 0; c < 64; ++c)
            acc += av[h * 64 + c] * w1[(size_t)(h * 64 + c) * 128 + k];
        U[(which * 8 + h) * 128 + k] = acc;
    }
    if (i < 512 * 128 / 4) {
        float4 v = ((const float4*)w1)[i];
        ushort2* o = (ushort2*)(o1 + i * 4);
        o[0] = make_ushort2(f2b(v.x), f2b(v.y));
        o[1] = make_ushort2(f2b(v.z), f2b(v.w));
    }
    if (i < 64 * 512 / 4) {
        float4 v = ((const float4*)w2)[i];
        ushort2* o = (ushort2*)(o2 + i * 4);
        o[0] = make_ushort2(f2b(v.x), f2b(v.y));
        o[1] = make_ushort2(f2b(v.z), f2b(v.w));
    }
    if (i < 64 * 64 / 4) {
        float4 v = ((const float4*)w3)[i];
        ushort2* o = (ushort2*)(o3 + i * 4);
        o[0] = make_ushort2(f2b(v.x), f2b(v.y));
        o[1] = make_ushort2(f2b(v.z), f2b(v.w));
    }
    if (i < N_NODES * 128 / 8) {
        const float4* xp = (const float4*)x + (size_t)i * 2;
        float4 v0 = xp[0], v1 = xp[1];
        unsigned int u0 = (unsigned int)f2b(v0.x) | ((unsigned int)f2b(v0.y) << 16);
        unsigned int u1 = (unsigned int)f2b(v0.z) | ((unsigned int)f2b(v0.w) << 16);
        unsigned int u2 = (unsigned int)f2b(v1.x) | ((unsigned int)f2b(v1.y) << 16);
        unsigned int u3 = (unsigned int)f2b(v1.z) | ((unsigned int)f2b(v1.w) << 16);
        *(uint4*)(xb + (size_t)i * 8) = make_uint4(u0, u1, u2, u3);
    }
}

// ---------------------------------------------------------------------------
// Attention logits from input space: asrc/adst[N,8] = xb[N,128] . U
// ---------------------------------------------------------------------------
__global__ __launch_bounds__(256) void k_attn(const unsigned short* __restrict__ xb,
                                              const float* __restrict__ U,
                                              float* __restrict__ asrc,
                                              float* __restrict__ adst) {
    __shared__ float sU[16 * 132];           // stride 132 floats
    __shared__ unsigned short sX[16 * 136];  // stride 136 shorts (16B-aligned rows)
    int t = threadIdx.x;
    for (int i = t; i < 2048; i += 256) sU[(i >> 7) * 132 + (i & 127)] = U[i];
    int n0 = blockIdx.x * 16;
    {
        int r = t >> 4, c = (t & 15) * 8;
        *(uint4*)&sX[r * 136 + c] = *(const uint4*)(xb + (size_t)(n0 + r) * 128 + c);
    }
    __syncthreads();
    int nl = t >> 4, o = t & 15;
    const unsigned short* xr = sX + nl * 136;
    const float* ur = sU + o * 132;
    float acc = 0.f;
#pragma unroll 8
    for (int k2 = 0; k2 < 128; ++k2) acc += b2f(xr[k2]) * ur[k2];
    int n = n0 + nl;
    if (o < 8) asrc[n * 8 + o] = acc;
    else       adst[n * 8 + (o - 8)] = acc;
}

// ---------------------------------------------------------------------------
// Edge-index dtype detection (reference int64 vs harness int32).
// ---------------------------------------------------------------------------
__global__ void k_detect(const int* __restrict__ idx, int* __restrict__ flag) {
    int i = blockIdx.x * blockDim.x + threadIdx.x;   // 8192 threads
    int v = idx[2 * i + 1];
    unsigned long long any = __ballot(v != 0);
    if ((threadIdx.x & 63) == 0 && any) atomicOr(flag, 1);   // 1 => int32 data
}

__device__ __forceinline__ int edge_src(const int* idx, int e, int is32) {
    return is32 ? idx[e] : idx[2 * e];
}
__device__ __forceinline__ int edge_dst(const int* idx, int e, int is32) {
    return is32 ? idx[N_EDGES + e] : idx[2 * (N_EDGES + e)];
}

// ---------------------------------------------------------------------------
// CSR build: degree -> 3-kernel scan (PADDED row starts) -> scatter
// ---------------------------------------------------------------------------
__global__ void k_degree(const int* __restrict__ idx, const int* __restrict__ flag,
                         int* __restrict__ deg) {
    int e = blockIdx.x * blockDim.x + threadIdx.x;
    if (e >= ETOT) return;
    int is32 = *flag;
    int d = (e < N_EDGES) ? edge_dst(idx, e, is32) : (e - N_EDGES);
    atomicAdd(&deg[d], 1);
}

__global__ __launch_bounds__(256) void k_scan1(const int* __restrict__ deg,
                                               int* __restrict__ rowptr,
                                               int* __restrict__ bsum) {
    __shared__ int sd[256];
    int t = threadIdx.x;
    int i = blockIdx.x * 256 + t;
    int v = (i < N_NODES) ? ((deg[i] + 3) & ~3) : 0;   // padded degree
    sd[t] = v;
    __syncthreads();
#pragma unroll
    for (int off = 1; off < 256; off <<= 1) {
        int a = (t >= off) ? sd[t - off] : 0;
        __syncthreads();
        sd[t] += a;
        __syncthreads();
    }
    if (i < N_NODES) rowptr[i] = sd[t] - v;
    if (t == 255) bsum[blockIdx.x] = sd[255];
}

__global__ __launch_bounds__(256) void k_scan2(int* __restrict__ bsum,
                                               int* __restrict__ boff,
                                               int* __restrict__ rowptr,
                                               int nb) {
    __shared__ int sd[256];
    int t = threadIdx.x;
    int v = (t < nb) ? bsum[t] : 0;
    sd[t] = v;
    __syncthreads();
#pragma unroll
    for (int off = 1; off < 256; off <<= 1) {
        int a = (t >= off) ? sd[t - off] : 0;
        __syncthreads();
        sd[t] += a;
        __syncthreads();
    }
    boff[t] = sd[t] - v;
    if (t == 255) rowptr[N_NODES] = sd[255];    // total padded length
}

__global__ __launch_bounds__(256) void k_scan3(int* __restrict__ rowptr,
                                               const int* __restrict__ boff,
                                               const int* __restrict__ deg,
                                               int* __restrict__ cursor,
                                               int* __restrict__ col) {
    int i = blockIdx.x * 256 + threadIdx.x;
    if (i == 0) {                                // zero 48-int tail pad
        int tot = rowptr[N_NODES];
        for (int q = 0; q < 48; ++q) col[tot + q] = 0;
    }
    if (i >= N_NODES) return;
    int r = rowptr[i] + boff[blockIdx.x];
    rowptr[i] = r;
    cursor[i] = r;
    int d = deg[i];
    int pd = (d + 3) & ~3;
    for (int p = r + d; p < r + pd; ++p) col[p] = 0;   // zero row pads
}

__global__ void k_scatter(const int* __restrict__ idx, const int* __restrict__ flag,
                          int* __restrict__ cursor, int* __restrict__ col) {
    int e = blockIdx.x * blockDim.x + threadIdx.x;
    if (e >= ETOT) return;
    int is32 = *flag;
    int s, d;
    if (e < N_EDGES) { s = edge_src(idx, e, is32); d = edge_dst(idx, e, is32); }
    else             { s = d = e - N_EDGES; }
    int pos = atomicAdd(&cursor[d], 1);
    col[pos] = s;
}

// ---------------------------------------------------------------------------
// Layer-1 aggregation in INPUT space (R3's proven VALU version, 256B/edge).
// NO LDS, no barriers — max occupancy for the latency-bound gather loop.
// ---------------------------------------------------------------------------
__device__ __forceinline__ void aggx_slot(int idx, int rem, float tt, unsigned int xx,
                                          float adn, float& ssum, f32x2* acc) {
    float e = tt + adn;
    e = fmaxf(e, 0.2f * e);
    float ex = __expf(e);
    ex = (idx < rem) ? ex : 0.f;
    ssum += ex;
    float fx = __uint_as_float(xx << 16);
    float fy = __uint_as_float(xx & 0xffff0000u);
    int exi = __float_as_int(ex);
#pragma unroll
    for (int hh = 0; hh < 8; ++hh) {
        float wh = __int_as_float(__builtin_amdgcn_readlane(exi, hh << 3));
        acc[hh].x = fmaf(fx, wh, acc[hh].x);
        acc[hh].y = fmaf(fy, wh, acc[hh].y);
    }
}

__global__ __launch_bounds__(256) void k_aggx(const unsigned short* __restrict__ xb,  // [N,128]
                                              const float* __restrict__ asrc,         // [N,8]
                                              const float* __restrict__ adst,         // [N,8]
                                              const int* __restrict__ rowptr,         // padded starts
                                              const int* __restrict__ degv,
                                              const int* __restrict__ col,
                                              unsigned short* __restrict__ aggX) {    // [N,1024]
    int n = blockIdx.x * 4 + (threadIdx.x >> 6);
    if (n >= N_NODES) return;
    int l = threadIdx.x & 63;
    int j = l >> 3;
    unsigned lx2 = (unsigned)(l << 1);
    int start = rowptr[n];
    int end   = start + degv[n];
    float adn = adst[((unsigned)n << 3) + (unsigned)j];

    float ssum = 0.f;
    f32x2 acc[8];
#pragma unroll
    for (int hh = 0; hh < 8; ++hh) acc[hh] = (f32x2){0.f, 0.f};

    float tA0, tA1, tA2, tA3, tB0, tB1, tB2, tB3;
    unsigned int xA0, xA1, xA2, xA3, xB0, xB1, xB2, xB3;
    int4 cA, cB;

#define GATHX(c, T0, T1, T2, T3, X0, X1, X2, X3)                              \
    T0 = asrc[(((unsigned)(c).x) << 3) + (unsigned)j];                        \
    T1 = asrc[(((unsigned)(c).y) << 3) + (unsigned)j];                        \
    T2 = asrc[(((unsigned)(c).z) << 3) + (unsigned)j];                        \
    T3 = asrc[(((unsigned)(c).w) << 3) + (unsigned)j];                        \
    X0 = *(const unsigned int*)(xb + (((unsigned)(c).x) << 7) + lx2);         \
    X1 = *(const unsigned int*)(xb + (((unsigned)(c).y) << 7) + lx2);         \
    X2 = *(const unsigned int*)(xb + (((unsigned)(c).z) << 7) + lx2);         \
    X3 = *(const unsigned int*)(xb + (((unsigned)(c).w) << 7) + lx2);

    int k = start;
    cA = *(const int4*)(col + k);
    cB = *(const int4*)(col + k + 4);
    GATHX(cA, tA0, tA1, tA2, tA3, xA0, xA1, xA2, xA3);
    for (;;) {
        bool hasB = (k + 4 < end);
        if (hasB) {
            GATHX(cB, tB0, tB1, tB2, tB3, xB0, xB1, xB2, xB3);
            cA = *(const int4*)(col + k + 8);
        }
        {
            int rem = end - k;
            aggx_slot(0, rem, tA0, xA0, adn, ssum, acc);
            aggx_slot(1, rem, tA1, xA1, adn, ssum, acc);
            aggx_slot(2, rem, tA2, xA2, adn, ssum, acc);
            aggx_slot(3, rem, tA3, xA3, adn, ssum, acc);
        }
        k += 4;
        if (!hasB) break;
        bool hasA = (k + 4 < end);
        if (hasA) {
            GATHX(cA, tA0, tA1, tA2, tA3, xA0, xA1, xA2, xA3);
            cB = *(const int4*)(col + k + 8);
        }
        {
            int rem = end - k;
            aggx_slot(0, rem, tB0, xB0, adn, ssum, acc);
            aggx_slot(1, rem, tB1, xB1, adn, ssum, acc);
            aggx_slot(2, rem, tB2, xB2, adn, ssum, acc);
            aggx_slot(3, rem, tB3, xB3, adn, ssum, acc);
        }
        k += 4;
        if (!hasA) break;
    }
#undef GATHX

    // normalize and store: per head, wave writes 256B contiguous
    size_t base = (size_t)n * 1024 + lx2;
#pragma unroll
    for (int hh = 0; hh < 8; ++hh) {
        float sh = __int_as_float(__builtin_amdgcn_readlane(__float_as_int(ssum), hh << 3));
        float iv = 1.f / (sh + 1e-16f);
        unsigned int lo = f2b(acc[hh].x * iv);
        unsigned int hi = f2b(acc[hh].y * iv);
        *(unsigned int*)(aggX + base + hh * 128) = lo | (hi << 16);
    }
}

// ---------------------------------------------------------------------------
// FUSED GEMM1+GEMM2, v2 (R9, best measured): 512 threads (8 waves), ONE
// barrier, 64-row tiles.
// Stage 1: wave w == head w. 64x64 head tile (64 MFMAs), A read directly
//   from global aggX (streamed once), B from L2-hot W1. ELU -> X2s[64][520].
// Stage 2: h2 = X2s @ W2^T. Wave w owns row-tile w>>1, col-tiles
//   {2(w&1), 2(w&1)+1}; split attention epilogue combines 2 waves/row-tile.
// ---------------------------------------------------------------------------
__global__ __launch_bounds__(512, 4) void k_gemm12(const unsigned short* __restrict__ aggX, // [N,1024]
                                                   const unsigned short* __restrict__ W1b,  // [512,128]
                                                   const float* __restrict__ b1,            // [512]
                                                   const unsigned short* __restrict__ W2b,  // [64,512]
                                                   const float* __restrict__ a2s,           // [64]
                                                   const float* __restrict__ a2d,           // [64]
                                                   unsigned short* __restrict__ h2,         // [N,64]
                                                   float* __restrict__ asb,                 // [N]
                                                   float* __restrict__ adb) {               // [N]
    __shared__ unsigned short X2s[64 * 520];   // 66560 B
    __shared__ float red_s[8][16];
    __shared__ float red_d[8][16];
    int t = threadIdx.x;
    int w = t >> 6, l = t & 63;
    int quad = l >> 4, lm = l & 15;
    int m0 = blockIdx.x * 64;

    // ---- stage 1: wave w computes head w's 64x64 tile, barrier-free ----
    {
        int h = w;
        f32x4 acc1[4][4];    // [row-tile][col-tile]
#pragma unroll
        for (int rt = 0; rt < 4; ++rt)
#pragma unroll
            for (int ct = 0; ct < 4; ++ct) acc1[rt][ct] = (f32x4){0.f, 0.f, 0.f, 0.f};

#pragma unroll
        for (int k0 = 0; k0 < 4; ++k0) {                 // K = 128, 4 steps of 32
            bf16x8 af[4];
#pragma unroll
            for (int rt = 0; rt < 4; ++rt) {
                int m = m0 + rt * 16 + lm;
                uint4 au = make_uint4(0, 0, 0, 0);
                if (m < N_NODES)
                    au = *(const uint4*)(aggX + (size_t)m * 1024 + h * 128 + k0 * 32 + quad * 8);
                af[rt] = *(bf16x8*)&au;
            }
#pragma unroll
            for (int ct = 0; ct < 4; ++ct) {
                uint4 bu = *(const uint4*)(W1b + (size_t)(h * 64 + ct * 16 + lm) * 128 + k0 * 32 + quad * 8);
                bf16x8 bf_ = *(bf16x8*)&bu;
#pragma unroll
                for (int rt = 0; rt < 4; ++rt)
                    acc1[rt][ct] = __builtin_amdgcn_mfma_f32_16x16x32_bf16(af[rt], bf_, acc1[rt][ct], 0, 0, 0);
            }
        }
        // bias + ELU -> X2s slab (cols h*64 .. h*64+63)
#pragma unroll
        for (int ct = 0; ct < 4; ++ct) {
            float bcol = b1[h * 64 + ct * 16 + lm];
#pragma unroll
            for (int rt = 0; rt < 4; ++rt)
#pragma unroll
                for (int g = 0; g < 4; ++g) {
                    float v = acc1[rt][ct][g] + bcol;
                    v = (v > 0.f) ? v : expm1f(v);
                    X2s[(rt * 16 + quad * 4 + g) * 520 + h * 64 + ct * 16 + lm] = f2b(v);
                }
        }
    }
    __syncthreads();

    // ---- stage 2: h2 tile = X2s @ W2^T; wave w: row-tile w>>1, 2 col-tiles ----
    int rt2 = w >> 1;
    int ct0 = (w & 1) * 2, ct1 = ct0 + 1;
    f32x4 acc2a = (f32x4){0.f, 0.f, 0.f, 0.f};
    f32x4 acc2b = (f32x4){0.f, 0.f, 0.f, 0.f};
#pragma unroll 4
    for (int k0 = 0; k0 < 512; k0 += 32) {
        bf16x8 af = *(const bf16x8*)&X2s[(rt2 * 16 + lm) * 520 + k0 + quad * 8];
        uint4 b0 = *(const uint4*)(W2b + (size_t)(ct0 * 16 + lm) * 512 + k0 + quad * 8);
        uint4 b1u = *(const uint4*)(W2b + (size_t)(ct1 * 16 + lm) * 512 + k0 + quad * 8);
        acc2a = __builtin_amdgcn_mfma_f32_16x16x32_bf16(af, *(bf16x8*)&b0, acc2a, 0, 0, 0);
        acc2b = __builtin_amdgcn_mfma_f32_16x16x32_bf16(af, *(bf16x8*)&b1u, acc2b, 0, 0, 0);
    }

    // h2 store (bf16)
#pragma unroll
    for (int g = 0; g < 4; ++g) {
        int m = m0 + rt2 * 16 + quad * 4 + g;
        if (m < N_NODES) {
            h2[(size_t)m * 64 + ct0 * 16 + lm] = f2b(acc2a[g]);
            h2[(size_t)m * 64 + ct1 * 16 + lm] = f2b(acc2b[g]);
        }
    }

    // layer-2 attention-coefficient epilogue (fp32 accumulators)
    {
        float as0 = a2s[ct0 * 16 + lm], ad0 = a2d[ct0 * 16 + lm];
        float as1 = a2s[ct1 * 16 + lm], ad1 = a2d[ct1 * 16 + lm];
#pragma unroll
        for (int g = 0; g < 4; ++g) {
            float vs = acc2a[g] * as0 + acc2b[g] * as1;
            float vd = acc2a[g] * ad0 + acc2b[g] * ad1;
#pragma unroll
            for (int off = 1; off < 16; off <<= 1) {
                vs += __shfl_xor(vs, off);
                vd += __shfl_xor(vd, off);
            }
            if (lm == 0) {
                red_s[w][quad * 4 + g] = vs;
                red_d[w][quad * 4 + g] = vd;
            }
        }
    }
    __syncthreads();
    if (t < 64) {
        int rt = t >> 4, rr = t & 15;
        float vs = red_s[2 * rt][rr] + red_s[2 * rt + 1][rr];
        float vd = red_d[2 * rt][rr] + red_d[2 * rt + 1][rr];
        int m = m0 + t;
        if (m < N_NODES) {
            asb[m] = vs;
            adb[m] = vd;
        }
    }
}

// ---------------------------------------------------------------------------
// bf16 MFMA GEMM: C[M,64] = A[M,K] @ W[64,K]^T. 64x64 tile, 4 waves.
// bf16 C store + attention-coefficient epilogue (layer 3).
// ---------------------------------------------------------------------------
__global__ __launch_bounds__(256) void k_gemm(const unsigned short* __restrict__ Ab,
                                              const unsigned short* __restrict__ W,
                                              unsigned short* __restrict__ C,
                                              const float* __restrict__ a_src,
                                              const float* __restrict__ a_dst,
                                              float* __restrict__ asb,
                                              float* __restrict__ adb,
                                              int M, int K, int Nout) {
    __shared__ unsigned short As[64 * 40];   // row stride 40 shorts (80 B)
    __shared__ unsigned short Bs[64 * 40];
    __shared__ float red_s[4][64];
    __shared__ float red_d[4][64];
    int t = threadIdx.x;
    int w = t >> 6, l = t & 63;
    int quad = l >> 4, lm = l & 15;
    int m0 = blockIdx.y * 64, n0 = blockIdx.x * 64;
    int lr = t >> 2;
    int lc = (t & 3) * 8;

    f32x4 acc[4];
#pragma unroll
    for (int r = 0; r < 4; ++r) acc[r] = (f32x4){0.f, 0.f, 0.f, 0.f};

    for (int k0 = 0; k0 < K; k0 += 32) {
        int m = m0 + lr;
        uint4 av = make_uint4(0, 0, 0, 0);
        if (m < M) av = *(const uint4*)(Ab + (size_t)m * K + k0 + lc);
        *(uint4*)&As[lr * 40 + lc] = av;
        uint4 bv = *(const uint4*)(W + (size_t)(n0 + lr) * K + k0 + lc);
        *(uint4*)&Bs[lr * 40 + lc] = bv;
        __syncthreads();

        bf16x8 bfrag = *(const bf16x8*)&Bs[(w * 16 + lm) * 40 + quad * 8];
#pragma unroll
        for (int r = 0; r < 4; ++r) {
            bf16x8 afrag = *(const bf16x8*)&As[(r * 16 + lm) * 40 + quad * 8];
            acc[r] = __builtin_amdgcn_mfma_f32_16x16x32_bf16(afrag, bfrag, acc[r], 0, 0, 0);
        }
        __syncthreads();
    }

    // C store (bf16)
#pragma unroll
    for (int r = 0; r < 4; ++r)
#pragma unroll
        for (int g = 0; g < 4; ++g) {
            int m = m0 + r * 16 + quad * 4 + g;
            if (m < M) C[(size_t)m * Nout + n0 + w * 16 + lm] = f2b(acc[r][g]);
        }

    // Attention-coefficient epilogue (fp32 accumulators)
    float as = a_src[w * 16 + lm];
    float ad = a_dst[w * 16 + lm];
#pragma unroll
    for (int r = 0; r < 4; ++r) {
#pragma unroll
        for (int g = 0; g < 4; ++g) {
            float vs = acc[r][g] * as;
            float vd = acc[r][g] * ad;
#pragma unroll
            for (int off = 1; off < 16; off <<= 1) {
                vs += __shfl_xor(vs, off);
                vd += __shfl_xor(vd, off);
            }
            if (lm == 0) {
                red_s[w][r * 16 + quad * 4 + g] = vs;
                red_d[w][r * 16 + quad * 4 + g] = vd;
            }
        }
    }
    __syncthreads();
    if (t < 64) {
        float vs = red_s[0][t] + red_s[1][t] + red_s[2][t] + red_s[3][t];
        float vd = red_d[0][t] + red_d[1][t] + red_d[2][t] + red_d[3][t];
        int m = m0 + t;
        if (m < M) {
            asb[m] = vs;
            adb[m] = vd;
        }
    }
}

// ---------------------------------------------------------------------------
// Fused segment-softmax + aggregation, H=1, C=64 (layers 2,3), bf16 h.
// v2: 4 edges per wave-step. Lane l = (group g = l>>4, chan-quad i = l&15).
// Group g handles edge-slot g of each padded 4-chunk; lane loads ushort4
// (channels 4i..4i+3, 8B). Same 128B/edge traffic, 4x fewer in-order steps
// per node. Cross-group shfl_xor(16/32) reduce; group 0 writes.
// ---------------------------------------------------------------------------
__global__ __launch_bounds__(256) void k_agg1(const unsigned short* __restrict__ h, // [N,64]
                                              const float* __restrict__ asrc,       // [N]
                                              const float* __restrict__ adst,       // [N]
                                              const int* __restrict__ rowptr,       // padded starts
                                              const int* __restrict__ degv,
                                              const int* __restrict__ col,
                                              const float* __restrict__ bias,       // [64]
                                              unsigned short* __restrict__ out) {   // [N,64]
    int n = blockIdx.x * 4 + (threadIdx.x >> 6);
    if (n >= N_NODES) return;
    int l = threadIdx.x & 63;
    int g = l >> 4;                    // edge-slot group 0..3
    int i = l & 15;                    // channel-quad index
    unsigned ci = (unsigned)(i << 2);  // channel base 4i
    int start = rowptr[n];
    int end   = start + degv[n];
    float adn = adst[n];

    float ssum = 0.f;
    f32x4 o4 = (f32x4){0.f, 0.f, 0.f, 0.f};

    int sA, sB;
    float tA, tB;
    ushort4 hA, hB;

#define AGG1_ACC(TT, HH, rem)                                                 \
    {                                                                         \
        float e = TT + adn;                                                   \
        e = fmaxf(e, 0.2f * e);                                               \
        float ex = __expf(e);                                                 \
        ex = (g < (rem)) ? ex : 0.f;                                          \
        ssum += ex;                                                           \
        o4[0] = fmaf(ex, b2f((HH).x), o4[0]);                                 \
        o4[1] = fmaf(ex, b2f((HH).y), o4[1]);                                 \
        o4[2] = fmaf(ex, b2f((HH).z), o4[2]);                                 \
        o4[3] = fmaf(ex, b2f((HH).w), o4[3]);                                 \
    }

    int k = start;
    sA = col[k + g];
    tA = asrc[sA];
    hA = *(const ushort4*)(h + (((unsigned)sA) << 6) + ci);
    for (;;) {
        bool hasB = (k + 4 < end);
        if (hasB) {
            sB = col[k + 4 + g];
            tB = asrc[sB];
            hB = *(const ushort4*)(h + (((unsigned)sB) << 6) + ci);
        }
        AGG1_ACC(tA, hA, end - k);
        k += 4;
        if (!hasB) break;
        bool hasA = (k + 4 < end);
        if (hasA) {
            sA = col[k + 4 + g];
            tA = asrc[sA];
            hA = *(const ushort4*)(h + (((unsigned)sA) << 6) + ci);
        }
        AGG1_ACC(tB, hB, end - k);
        k += 4;
        if (!hasA) break;
    }
#undef AGG1_ACC

    // combine the 4 edge-slot groups
    ssum += __shfl_xor(ssum, 16);
    ssum += __shfl_xor(ssum, 32);
#pragma unroll
    for (int c = 0; c < 4; ++c) {
        o4[c] += __shfl_xor(o4[c], 16);
        o4[c] += __shfl_xor(o4[c], 32);
    }

    if (g == 0) {
        float inv = 1.f / (ssum + 1e-16f);
        float4 bv = *(const float4*)(bias + ci);
        float v0 = o4[0] * inv + bv.x; v0 = (v0 > 0.f) ? v0 : expm1f(v0);
        float v1 = o4[1] * inv + bv.y; v1 = (v1 > 0.f) ? v1 : expm1f(v1);
        float v2 = o4[2] * inv + bv.z; v2 = (v2 > 0.f) ? v2 : expm1f(v2);
        float v3 = o4[3] * inv + bv.w; v3 = (v3 > 0.f) ? v3 : expm1f(v3);
        ushort4 ov = make_ushort4(f2b(v0), f2b(v1), f2b(v2), f2b(v3));
        *(ushort4*)(out + (size_t)n * 64 + ci) = ov;
    }
}

// ---------------------------------------------------------------------------
// Classifier: out[N,10] = h[N,64](bf16) @ Wc[10,64]^T + bc, fp32 out.
// ---------------------------------------------------------------------------
__global__ __launch_bounds__(256) void k_classifier(const unsigned short* __restrict__ h,
                                                    const float* __restrict__ Wc,
                                                    const float* __restrict__ bc,
                                                    float* __restrict__ out) {
    __shared__ float sW[640];
    for (int i = threadIdx.x; i < 640; i += blockDim.x) sW[i] = Wc[i];
    __syncthreads();
    int idx = blockIdx.x * blockDim.x + threadIdx.x;
    if (idx >= N_NODES * 10) return;
    int n = idx / 10, d = idx - n * 10;
    const unsigned short* hr = h + (size_t)n * 64;
    const float* wr = sW + d * 64;
    float acc = 0.f;
#pragma unroll
    for (int c = 0; c < 64; ++c) acc += b2f(hr[c]) * wr[c];
    out[idx] = acc + bc[d];
}

// ---------------------------------------------------------------------------
extern "C" void kernel_launch(void* const* d_in, const int* in_sizes, int n_in,
                              void* d_out, int out_size, void* d_ws, size_t ws_size,
                              hipStream_t stream) {
    const float* x    = (const float*)d_in[0];
    const int*   eidx = (const int*)  d_in[1];
    const float* W1   = (const float*)d_in[2];
    const float* a1s  = (const float*)d_in[3];
    const float* a1d  = (const float*)d_in[4];
    const float* b1   = (const float*)d_in[5];
    const float* W2   = (const float*)d_in[6];
    const float* a2s  = (const float*)d_in[7];
    const float* a2d  = (const float*)d_in[8];
    const float* b2   = (const float*)d_in[9];
    const float* W3   = (const float*)d_in[10];
    const float* a3s  = (const float*)d_in[11];
    const float* a3d  = (const float*)d_in[12];
    const float* b3   = (const float*)d_in[13];
    const float* Wc   = (const float*)d_in[14];
    const float* bc   = (const float*)d_in[15];
    float* out = (float*)d_out;

    // Workspace layout
    float* asbuf = (float*)d_ws;                              // N*8 fp32
    float* adbuf = asbuf + (size_t)N_NODES * 8;               // N*8 fp32
    unsigned short* aggX = (unsigned short*)(adbuf + (size_t)N_NODES * 8); // N*1024
    unsigned short* h2  = aggX + (size_t)N_NODES * 1024;      // N*64
    unsigned short* x3  = h2  + (size_t)N_NODES * 64;         // N*64
    unsigned short* h3  = x3  + (size_t)N_NODES * 64;         // N*64
    unsigned short* x4  = h3  + (size_t)N_NODES * 64;         // N*64
    unsigned short* xb  = x4  + (size_t)N_NODES * 64;         // N*128 (bf16 x)
    unsigned short* W1b = xb  + (size_t)N_NODES * 128;        // 512*128
    unsigned short* W2b = W1b + 512 * 128;                    // 64*512
    unsigned short* W3b = W2b + 64 * 512;                     // 64*64
    float* U    = (float*)(W3b + 64 * 64);                    // 16*128 fp32
    int* ibase  = (int*)(U + 16 * 128);
    int* deg    = ibase;                                      // N (zeroed in k_prep)
    int* flag   = deg + N_NODES;                              // 1
    int* rowptr = flag + 1;                                   // N+1 (padded starts)
    int* cursor = rowptr + N_NODES + 1;                       // N
    int* bsum   = cursor + N_NODES;                           // 256
    int* boff   = bsum + 256;                                 // 256
    int* col    = boff + 256;                                 // COL_CAP

    dim3 blk(256);
    const int SCAN_BLOCKS = (N_NODES + 255) / 256;            // 196
    const int PREP_BLOCKS = (N_NODES * 128 / 8 + 255) / 256;  // 3125

    // Prep: casts + U + attention logits (independent of CSR)
    k_prep<<<PREP_BLOCKS, blk, 0, stream>>>(x, W1, W2, W3, a1s, a1d,
                                            xb, W1b, W2b, W3b, U, deg, flag);
    k_attn<<<N_NODES / 16, blk, 0, stream>>>(xb, U, asbuf, adbuf);

    // CSR build
    k_detect<<<32, blk, 0, stream>>>(eidx, flag);
    k_degree<<<(ETOT + 255) / 256, blk, 0, stream>>>(eidx, flag, deg);
    k_scan1<<<SCAN_BLOCKS, blk, 0, stream>>>(deg, rowptr, bsum);
    k_scan2<<<1, blk, 0, stream>>>(bsum, boff, rowptr, SCAN_BLOCKS);
    k_scan3<<<SCAN_BLOCKS, blk, 0, stream>>>(rowptr, boff, deg, cursor, col);
    k_scatter<<<(ETOT + 255) / 256, blk, 0, stream>>>(eidx, flag, cursor, col);

    int mblocks   = (N_NODES + 63) / 64;   // 782
    int nblocks   = N_NODES / 4;           // 12500 (exact)

    // Layer 1 agg (VALU, input space) -> aggX
    k_aggx<<<nblocks, blk, 0, stream>>>(xb, asbuf, adbuf, rowptr, deg, col, aggX);

    // Fused GEMM1+GEMM2 (v2: 64-row tiles, 8 waves, 1 barrier)
    k_gemm12<<<mblocks, dim3(512), 0, stream>>>(aggX, W1b, b1, W2b, a2s, a2d,
                                                h2, asbuf, adbuf);

    // Layer 2 agg: h2 -> x3
    k_agg1<<<nblocks, blk, 0, stream>>>(h2, asbuf, adbuf, rowptr, deg, col, b2, x3);

    // Layer 3: x3[N,64] -> h3[N,64] (+ attn coefs); agg -> x4
    k_gemm<<<dim3(1, mblocks), blk, 0, stream>>>(x3, W3b, h3,
                                                 a3s, a3d, asbuf, adbuf,
                                                 N_NODES, 64, 64);
    k_agg1<<<nblocks, blk, 0, stream>>>(h3, asbuf, adbuf, rowptr, deg, col, b3, x4);

    // Classifier
    k_classifier<<<(N_NODES * 10 + 255) / 256, blk, 0, stream>>>(x4, Wc, bc, out);
}

// Round 12
// 432.284 us; speedup vs baseline: 1.0638x; 1.0261x over previous
//
#include <hip/hip_runtime.h>
#include <math.h>

#define N_NODES 50000
#define N_EDGES 800000
#define ETOT    (N_EDGES + N_NODES)   // 850000, with self loops
// col array: padded rows (each row padded to multiple of 4) + 64-int tail
#define COL_CAP (ETOT + 3 * N_NODES + 64)

typedef short bf16x8 __attribute__((ext_vector_type(8)));
typedef float f32x4  __attribute__((ext_vector_type(4)));
typedef float f32x2  __attribute__((ext_vector_type(2)));

__device__ __forceinline__ float b2f(unsigned int u16) {   // low 16 bits hold bf16
    return __uint_as_float(u16 << 16);
}
__device__ __forceinline__ unsigned short f2b(float f) {   // RNE
    unsigned int u = __float_as_uint(f);
    u += 0x7fffu + ((u >> 16) & 1u);
    return (unsigned short)(u >> 16);
}

// ---------------------------------------------------------------------------
// Prep: zero deg+flag, cast W1/W2/W3 fp32->bf16, cast x fp32->bf16,
// and (blocks 0..7) build U[16][128]: rows 0..7 = W1_h^T a1_src_h,
// rows 8..15 = W1_h^T a1_dst_h (fp32).
// ---------------------------------------------------------------------------
__global__ __launch_bounds__(256) void k_prep(const float* __restrict__ x,
                                              const float* __restrict__ w1,
                                              const float* __restrict__ w2,
                                              const float* __restrict__ w3,
                                              const float* __restrict__ a1s,
                                              const float* __restrict__ a1d,
                                              unsigned short* __restrict__ xb,
                                              unsigned short* __restrict__ o1,
                                              unsigned short* __restrict__ o2,
                                              unsigned short* __restrict__ o3,
                                              float* __restrict__ U,
                                              int* __restrict__ deg,
                                              int* __restrict__ flag) {
    int i = blockIdx.x * 256 + threadIdx.x;
    if (i < N_NODES) deg[i] = 0;
    if (i == 0) *flag = 0;
    if (blockIdx.x < 8) {
        int h = blockIdx.x;
        int which = threadIdx.x >> 7, k = threadIdx.x & 127;
        const float* av = which ? a1d : a1s;
        float acc = 0.f;
        for (int c = 0; c < 64; ++c)
            acc += av[h * 64 + c] * w1[(size_t)(h * 64 + c) * 128 + k];
        U[(which * 8 + h) * 128 + k] = acc;
    }
    if (i < 512 * 128 / 4) {
        float4 v = ((const float4*)w1)[i];
        ushort2* o = (ushort2*)(o1 + i * 4);
        o[0] = make_ushort2(f2b(v.x), f2b(v.y));
        o[1] = make_ushort2(f2b(v.z), f2b(v.w));
    }
    if (i < 64 * 512 / 4) {
        float4 v = ((const float4*)w2)[i];
        ushort2* o = (ushort2*)(o2 + i * 4);
        o[0] = make_ushort2(f2b(v.x), f2b(v.y));
        o[1] = make_ushort2(f2b(v.z), f2b(v.w));
    }
    if (i < 64 * 64 / 4) {
        float4 v = ((const float4*)w3)[i];
        ushort2* o = (ushort2*)(o3 + i * 4);
        o[0] = make_ushort2(f2b(v.x), f2b(v.y));
        o[1] = make_ushort2(f2b(v.z), f2b(v.w));
    }
    if (i < N_NODES * 128 / 8) {
        const float4* xp = (const float4*)x + (size_t)i * 2;
        float4 v0 = xp[0], v1 = xp[1];
        unsigned int u0 = (unsigned int)f2b(v0.x) | ((unsigned int)f2b(v0.y) << 16);
        unsigned int u1 = (unsigned int)f2b(v0.z) | ((unsigned int)f2b(v0.w) << 16);
        unsigned int u2 = (unsigned int)f2b(v1.x) | ((unsigned int)f2b(v1.y) << 16);
        unsigned int u3 = (unsigned int)f2b(v1.z) | ((unsigned int)f2b(v1.w) << 16);
        *(uint4*)(xb + (size_t)i * 8) = make_uint4(u0, u1, u2, u3);
    }
}

// ---------------------------------------------------------------------------
// Attention logits from input space: asrc/adst[N,8] = xb[N,128] . U
// ---------------------------------------------------------------------------
__global__ __launch_bounds__(256) void k_attn(const unsigned short* __restrict__ xb,
                                              const float* __restrict__ U,
                                              float* __restrict__ asrc,
                                              float* __restrict__ adst) {
    __shared__ float sU[16 * 132];           // stride 132 floats
    __shared__ unsigned short sX[16 * 136];  // stride 136 shorts (16B-aligned rows)
    int t = threadIdx.x;
    for (int i = t; i < 2048; i += 256) sU[(i >> 7) * 132 + (i & 127)] = U[i];
    int n0 = blockIdx.x * 16;
    {
        int r = t >> 4, c = (t & 15) * 8;
        *(uint4*)&sX[r * 136 + c] = *(const uint4*)(xb + (size_t)(n0 + r) * 128 + c);
    }
    __syncthreads();
    int nl = t >> 4, o = t & 15;
    const unsigned short* xr = sX + nl * 136;
    const float* ur = sU + o * 132;
    float acc = 0.f;
#pragma unroll 8
    for (int k2 = 0; k2 < 128; ++k2) acc += b2f(xr[k2]) * ur[k2];
    int n = n0 + nl;
    if (o < 8) asrc[n * 8 + o] = acc;
    else       adst[n * 8 + (o - 8)] = acc;
}

// ---------------------------------------------------------------------------
// Edge-index dtype detection (reference int64 vs harness int32).
// ---------------------------------------------------------------------------
__global__ void k_detect(const int* __restrict__ idx, int* __restrict__ flag) {
    int i = blockIdx.x * blockDim.x + threadIdx.x;   // 8192 threads
    int v = idx[2 * i + 1];
    unsigned long long any = __ballot(v != 0);
    if ((threadIdx.x & 63) == 0 && any) atomicOr(flag, 1);   // 1 => int32 data
}

__device__ __forceinline__ int edge_src(const int* idx, int e, int is32) {
    return is32 ? idx[e] : idx[2 * e];
}
__device__ __forceinline__ int edge_dst(const int* idx, int e, int is32) {
    return is32 ? idx[N_EDGES + e] : idx[2 * (N_EDGES + e)];
}

// ---------------------------------------------------------------------------
// CSR build: degree -> 3-kernel scan (PADDED row starts) -> scatter
// ---------------------------------------------------------------------------
__global__ void k_degree(const int* __restrict__ idx, const int* __restrict__ flag,
                         int* __restrict__ deg) {
    int e = blockIdx.x * blockDim.x + threadIdx.x;
    if (e >= ETOT) return;
    int is32 = *flag;
    int d = (e < N_EDGES) ? edge_dst(idx, e, is32) : (e - N_EDGES);
    atomicAdd(&deg[d], 1);
}

__global__ __launch_bounds__(256) void k_scan1(const int* __restrict__ deg,
                                               int* __restrict__ rowptr,
                                               int* __restrict__ bsum) {
    __shared__ int sd[256];
    int t = threadIdx.x;
    int i = blockIdx.x * 256 + t;
    int v = (i < N_NODES) ? ((deg[i] + 3) & ~3) : 0;   // padded degree
    sd[t] = v;
    __syncthreads();
#pragma unroll
    for (int off = 1; off < 256; off <<= 1) {
        int a = (t >= off) ? sd[t - off] : 0;
        __syncthreads();
        sd[t] += a;
        __syncthreads();
    }
    if (i < N_NODES) rowptr[i] = sd[t] - v;
    if (t == 255) bsum[blockIdx.x] = sd[255];
}

__global__ __launch_bounds__(256) void k_scan2(int* __restrict__ bsum,
                                               int* __restrict__ boff,
                                               int* __restrict__ rowptr,
                                               int nb) {
    __shared__ int sd[256];
    int t = threadIdx.x;
    int v = (t < nb) ? bsum[t] : 0;
    sd[t] = v;
    __syncthreads();
#pragma unroll
    for (int off = 1; off < 256; off <<= 1) {
        int a = (t >= off) ? sd[t - off] : 0;
        __syncthreads();
        sd[t] += a;
        __syncthreads();
    }
    boff[t] = sd[t] - v;
    if (t == 255) rowptr[N_NODES] = sd[255];    // total padded length
}

__global__ __launch_bounds__(256) void k_scan3(int* __restrict__ rowptr,
                                               const int* __restrict__ boff,
                                               const int* __restrict__ deg,
                                               int* __restrict__ cursor,
                                               int* __restrict__ col) {
    int i = blockIdx.x * 256 + threadIdx.x;
    if (i == 0) {                                // zero 48-int tail pad
        int tot = rowptr[N_NODES];
        for (int q = 0; q < 48; ++q) col[tot + q] = 0;
    }
    if (i >= N_NODES) return;
    int r = rowptr[i] + boff[blockIdx.x];
    rowptr[i] = r;
    cursor[i] = r;
    int d = deg[i];
    int pd = (d + 3) & ~3;
    for (int p = r + d; p < r + pd; ++p) col[p] = 0;   // zero row pads
}

__global__ void k_scatter(const int* __restrict__ idx, const int* __restrict__ flag,
                          int* __restrict__ cursor, int* __restrict__ col) {
    int e = blockIdx.x * blockDim.x + threadIdx.x;
    if (e >= ETOT) return;
    int is32 = *flag;
    int s, d;
    if (e < N_EDGES) { s = edge_src(idx, e, is32); d = edge_dst(idx, e, is32); }
    else             { s = d = e - N_EDGES; }
    int pos = atomicAdd(&cursor[d], 1);
    col[pos] = s;
}

// ---------------------------------------------------------------------------
// Layer-1 aggregation in INPUT space (R3 structure, 256B/edge gathers).
// v4: packed-FMA accumulate. Lane l holds channels {2l,2l+1} for all 8 heads
// (8 x f32x2 acc). Per edge: one exp per lane group (head j = l>>3),
// broadcast via readlane into an SGPR, duplicated into an SGPR PAIR by SALU
// (co-issues with VALU), then 8 x v_pk_fma_f32 replace 16 scalar FMAs.
// Bit-identical math to v1 (same fma per channel, same edge order).
// NO LDS, no barriers — max occupancy for the latency-bound gather loop.
// ---------------------------------------------------------------------------
__device__ __forceinline__ void aggx_slot(int idx, int rem, float tt, unsigned int xx,
                                          float adn, float& ssum, f32x2* acc) {
    float e = tt + adn;
    e = fmaxf(e, 0.2f * e);
    float ex = __expf(e);
    ex = (idx < rem) ? ex : 0.f;
    ssum += ex;
    f32x2 fxy;
    fxy.x = __uint_as_float(xx << 16);
    fxy.y = __uint_as_float(xx & 0xffff0000u);
    int exi = __float_as_int(ex);
#pragma unroll
    for (int hh = 0; hh < 8; ++hh) {
        unsigned int wu = (unsigned int)__builtin_amdgcn_readlane(exi, hh << 3);
        unsigned long long wp = (unsigned long long)wu | ((unsigned long long)wu << 32);
        asm("v_pk_fma_f32 %0, %1, %2, %0" : "+v"(acc[hh]) : "v"(fxy), "s"(wp));
    }
}

__global__ __launch_bounds__(256) void k_aggx(const unsigned short* __restrict__ xb,  // [N,128]
                                              const float* __restrict__ asrc,         // [N,8]
                                              const float* __restrict__ adst,         // [N,8]
                                              const int* __restrict__ rowptr,         // padded starts
                                              const int* __restrict__ degv,
                                              const int* __restrict__ col,
                                              unsigned short* __restrict__ aggX) {    // [N,1024]
    int n = blockIdx.x * 4 + (threadIdx.x >> 6);
    if (n >= N_NODES) return;
    int l = threadIdx.x & 63;
    int j = l >> 3;
    unsigned lx2 = (unsigned)(l << 1);
    int start = rowptr[n];
    int end   = start + degv[n];
    float adn = adst[((unsigned)n << 3) + (unsigned)j];

    float ssum = 0.f;
    f32x2 acc[8];
#pragma unroll
    for (int hh = 0; hh < 8; ++hh) acc[hh] = (f32x2){0.f, 0.f};

    float tA0, tA1, tA2, tA3, tB0, tB1, tB2, tB3;
    unsigned int xA0, xA1, xA2, xA3, xB0, xB1, xB2, xB3;
    int4 cA, cB;

#define GATHX(c, T0, T1, T2, T3, X0, X1, X2, X3)                              \
    T0 = asrc[(((unsigned)(c).x) << 3) + (unsigned)j];                        \
    T1 = asrc[(((unsigned)(c).y) << 3) + (unsigned)j];                        \
    T2 = asrc[(((unsigned)(c).z) << 3) + (unsigned)j];                        \
    T3 = asrc[(((unsigned)(c).w) << 3) + (unsigned)j];                        \
    X0 = *(const unsigned int*)(xb + (((unsigned)(c).x) << 7) + lx2);         \
    X1 = *(const unsigned int*)(xb + (((unsigned)(c).y) << 7) + lx2);         \
    X2 = *(const unsigned int*)(xb + (((unsigned)(c).z) << 7) + lx2);         \
    X3 = *(const unsigned int*)(xb + (((unsigned)(c).w) << 7) + lx2);

    int k = start;
    cA = *(const int4*)(col + k);
    cB = *(const int4*)(col + k + 4);
    GATHX(cA, tA0, tA1, tA2, tA3, xA0, xA1, xA2, xA3);
    for (;;) {
        bool hasB = (k + 4 < end);
        if (hasB) {
            GATHX(cB, tB0, tB1, tB2, tB3, xB0, xB1, xB2, xB3);
            cA = *(const int4*)(col + k + 8);
        }
        {
            int rem = end - k;
            aggx_slot(0, rem, tA0, xA0, adn, ssum, acc);
            aggx_slot(1, rem, tA1, xA1, adn, ssum, acc);
            aggx_slot(2, rem, tA2, xA2, adn, ssum, acc);
            aggx_slot(3, rem, tA3, xA3, adn, ssum, acc);
        }
        k += 4;
        if (!hasB) break;
        bool hasA = (k + 4 < end);
        if (hasA) {
            GATHX(cA, tA0, tA1, tA2, tA3, xA0, xA1, xA2, xA3);
            cB = *(const int4*)(col + k + 8);
        }
        {
            int rem = end - k;
            aggx_slot(0, rem, tB0, xB0, adn, ssum, acc);
            aggx_slot(1, rem, tB1, xB1, adn, ssum, acc);
            aggx_slot(2, rem, tB2, xB2, adn, ssum, acc);
            aggx_slot(3, rem, tB3, xB3, adn, ssum, acc);
        }
        k += 4;
        if (!hasA) break;
    }
#undef GATHX

    // normalize and store: per head, wave writes 256B contiguous
    size_t base = (size_t)n * 1024 + lx2;
#pragma unroll
    for (int hh = 0; hh < 8; ++hh) {
        float sh = __int_as_float(__builtin_amdgcn_readlane(__float_as_int(ssum), hh << 3));
        float iv = 1.f / (sh + 1e-16f);
        unsigned int lo = f2b(acc[hh].x * iv);
        unsigned int hi = f2b(acc[hh].y * iv);
        *(unsigned int*)(aggX + base + hh * 128) = lo | (hi << 16);
    }
}

// ---------------------------------------------------------------------------
// FUSED GEMM1+GEMM2, v2 (R9, best measured): 512 threads (8 waves), ONE
// barrier, 64-row tiles.
// Stage 1: wave w == head w. 64x64 head tile (64 MFMAs), A read directly
//   from global aggX (streamed once), B from L2-hot W1. ELU -> X2s[64][520].
// Stage 2: h2 = X2s @ W2^T. Wave w owns row-tile w>>1, col-tiles
//   {2(w&1), 2(w&1)+1}; split attention epilogue combines 2 waves/row-tile.
// ---------------------------------------------------------------------------
__global__ __launch_bounds__(512, 4) void k_gemm12(const unsigned short* __restrict__ aggX, // [N,1024]
                                                   const unsigned short* __restrict__ W1b,  // [512,128]
                                                   const float* __restrict__ b1,            // [512]
                                                   const unsigned short* __restrict__ W2b,  // [64,512]
                                                   const float* __restrict__ a2s,           // [64]
                                                   const float* __restrict__ a2d,           // [64]
                                                   unsigned short* __restrict__ h2,         // [N,64]
                                                   float* __restrict__ asb,                 // [N]
                                                   float* __restrict__ adb) {               // [N]
    __shared__ unsigned short X2s[64 * 520];   // 66560 B
    __shared__ float red_s[8][16];
    __shared__ float red_d[8][16];
    int t = threadIdx.x;
    int w = t >> 6, l = t & 63;
    int quad = l >> 4, lm = l & 15;
    int m0 = blockIdx.x * 64;

    // ---- stage 1: wave w computes head w's 64x64 tile, barrier-free ----
    {
        int h = w;
        f32x4 acc1[4][4];    // [row-tile][col-tile]
#pragma unroll
        for (int rt = 0; rt < 4; ++rt)
#pragma unroll
            for (int ct = 0; ct < 4; ++ct) acc1[rt][ct] = (f32x4){0.f, 0.f, 0.f, 0.f};

#pragma unroll
        for (int k0 = 0; k0 < 4; ++k0) {                 // K = 128, 4 steps of 32
            bf16x8 af[4];
#pragma unroll
            for (int rt = 0; rt < 4; ++rt) {
                int m = m0 + rt * 16 + lm;
                uint4 au = make_uint4(0, 0, 0, 0);
                if (m < N_NODES)
                    au = *(const uint4*)(aggX + (size_t)m * 1024 + h * 128 + k0 * 32 + quad * 8);
                af[rt] = *(bf16x8*)&au;
            }
#pragma unroll
            for (int ct = 0; ct < 4; ++ct) {
                uint4 bu = *(const uint4*)(W1b + (size_t)(h * 64 + ct * 16 + lm) * 128 + k0 * 32 + quad * 8);
                bf16x8 bf_ = *(bf16x8*)&bu;
#pragma unroll
                for (int rt = 0; rt < 4; ++rt)
                    acc1[rt][ct] = __builtin_amdgcn_mfma_f32_16x16x32_bf16(af[rt], bf_, acc1[rt][ct], 0, 0, 0);
            }
        }
        // bias + ELU -> X2s slab (cols h*64 .. h*64+63)
#pragma unroll
        for (int ct = 0; ct < 4; ++ct) {
            float bcol = b1[h * 64 + ct * 16 + lm];
#pragma unroll
            for (int rt = 0; rt < 4; ++rt)
#pragma unroll
                for (int g = 0; g < 4; ++g) {
                    float v = acc1[rt][ct][g] + bcol;
                    v = (v > 0.f) ? v : expm1f(v);
                    X2s[(rt * 16 + quad * 4 + g) * 520 + h * 64 + ct * 16 + lm] = f2b(v);
                }
        }
    }
    __syncthreads();

    // ---- stage 2: h2 tile = X2s @ W2^T; wave w: row-tile w>>1, 2 col-tiles ----
    int rt2 = w >> 1;
    int ct0 = (w & 1) * 2, ct1 = ct0 + 1;
    f32x4 acc2a = (f32x4){0.f, 0.f, 0.f, 0.f};
    f32x4 acc2b = (f32x4){0.f, 0.f, 0.f, 0.f};
#pragma unroll 4
    for (int k0 = 0; k0 < 512; k0 += 32) {
        bf16x8 af = *(const bf16x8*)&X2s[(rt2 * 16 + lm) * 520 + k0 + quad * 8];
        uint4 b0 = *(const uint4*)(W2b + (size_t)(ct0 * 16 + lm) * 512 + k0 + quad * 8);
        uint4 b1u = *(const uint4*)(W2b + (size_t)(ct1 * 16 + lm) * 512 + k0 + quad * 8);
        acc2a = __builtin_amdgcn_mfma_f32_16x16x32_bf16(af, *(bf16x8*)&b0, acc2a, 0, 0, 0);
        acc2b = __builtin_amdgcn_mfma_f32_16x16x32_bf16(af, *(bf16x8*)&b1u, acc2b, 0, 0, 0);
    }

    // h2 store (bf16)
#pragma unroll
    for (int g = 0; g < 4; ++g) {
        int m = m0 + rt2 * 16 + quad * 4 + g;
        if (m < N_NODES) {
            h2[(size_t)m * 64 + ct0 * 16 + lm] = f2b(acc2a[g]);
            h2[(size_t)m * 64 + ct1 * 16 + lm] = f2b(acc2b[g]);
        }
    }

    // layer-2 attention-coefficient epilogue (fp32 accumulators)
    {
        float as0 = a2s[ct0 * 16 + lm], ad0 = a2d[ct0 * 16 + lm];
        float as1 = a2s[ct1 * 16 + lm], ad1 = a2d[ct1 * 16 + lm];
#pragma unroll
        for (int g = 0; g < 4; ++g) {
            float vs = acc2a[g] * as0 + acc2b[g] * as1;
            float vd = acc2a[g] * ad0 + acc2b[g] * ad1;
#pragma unroll
            for (int off = 1; off < 16; off <<= 1) {
                vs += __shfl_xor(vs, off);
                vd += __shfl_xor(vd, off);
            }
            if (lm == 0) {
                red_s[w][quad * 4 + g] = vs;
                red_d[w][quad * 4 + g] = vd;
            }
        }
    }
    __syncthreads();
    if (t < 64) {
        int rt = t >> 4, rr = t & 15;
        float vs = red_s[2 * rt][rr] + red_s[2 * rt + 1][rr];
        float vd = red_d[2 * rt][rr] + red_d[2 * rt + 1][rr];
        int m = m0 + t;
        if (m < N_NODES) {
            asb[m] = vs;
            adb[m] = vd;
        }
    }
}

// ---------------------------------------------------------------------------
// bf16 MFMA GEMM: C[M,64] = A[M,K] @ W[64,K]^T. 64x64 tile, 4 waves.
// bf16 C store + attention-coefficient epilogue (layer 3).
// ---------------------------------------------------------------------------
__global__ __launch_bounds__(256) void k_gemm(const unsigned short* __restrict__ Ab,
                                              const unsigned short* __restrict__ W,
                                              unsigned short* __restrict__ C,
                                              const float* __restrict__ a_src,
                                              const float* __restrict__ a_dst,
                                              float* __restrict__ asb,
                                              float* __restrict__ adb,
                                              int M, int K, int Nout) {
    __shared__ unsigned short As[64 * 40];   // row stride 40 shorts (80 B)
    __shared__ unsigned short Bs[64 * 40];
    __shared__ float red_s[4][64];
    __shared__ float red_d[4][64];
    int t = threadIdx.x;
    int w = t >> 6, l = t & 63;
    int quad = l >> 4, lm = l & 15;
    int m0 = blockIdx.y * 64, n0 = blockIdx.x * 64;
    int lr = t >> 2;
    int lc = (t & 3) * 8;

    f32x4 acc[4];
#pragma unroll
    for (int r = 0; r < 4; ++r) acc[r] = (f32x4){0.f, 0.f, 0.f, 0.f};

    for (int k0 = 0; k0 < K; k0 += 32) {
        int m = m0 + lr;
        uint4 av = make_uint4(0, 0, 0, 0);
        if (m < M) av = *(const uint4*)(Ab + (size_t)m * K + k0 + lc);
        *(uint4*)&As[lr * 40 + lc] = av;
        uint4 bv = *(const uint4*)(W + (size_t)(n0 + lr) * K + k0 + lc);
        *(uint4*)&Bs[lr * 40 + lc] = bv;
        __syncthreads();

        bf16x8 bfrag = *(const bf16x8*)&Bs[(w * 16 + lm) * 40 + quad * 8];
#pragma unroll
        for (int r = 0; r < 4; ++r) {
            bf16x8 afrag = *(const bf16x8*)&As[(r * 16 + lm) * 40 + quad * 8];
            acc[r] = __builtin_amdgcn_mfma_f32_16x16x32_bf16(afrag, bfrag, acc[r], 0, 0, 0);
        }
        __syncthreads();
    }

    // C store (bf16)
#pragma unroll
    for (int r = 0; r < 4; ++r)
#pragma unroll
        for (int g = 0; g < 4; ++g) {
            int m = m0 + r * 16 + quad * 4 + g;
            if (m < M) C[(size_t)m * Nout + n0 + w * 16 + lm] = f2b(acc[r][g]);
        }

    // Attention-coefficient epilogue (fp32 accumulators)
    float as = a_src[w * 16 + lm];
    float ad = a_dst[w * 16 + lm];
#pragma unroll
    for (int r = 0; r < 4; ++r) {
#pragma unroll
        for (int g = 0; g < 4; ++g) {
            float vs = acc[r][g] * as;
            float vd = acc[r][g] * ad;
#pragma unroll
            for (int off = 1; off < 16; off <<= 1) {
                vs += __shfl_xor(vs, off);
                vd += __shfl_xor(vd, off);
            }
            if (lm == 0) {
                red_s[w][r * 16 + quad * 4 + g] = vs;
                red_d[w][r * 16 + quad * 4 + g] = vd;
            }
        }
    }
    __syncthreads();
    if (t < 64) {
        float vs = red_s[0][t] + red_s[1][t] + red_s[2][t] + red_s[3][t];
        float vd = red_d[0][t] + red_d[1][t] + red_d[2][t] + red_d[3][t];
        int m = m0 + t;
        if (m < M) {
            asb[m] = vs;
            adb[m] = vd;
        }
    }
}

// ---------------------------------------------------------------------------
// Fused segment-softmax + aggregation, H=1, C=64 (layers 2,3), bf16 h.
// v1 (R9, best measured): 2-deep pipeline over padded 4-edge groups,
// one edge per wave-step, lane = channel.
// ---------------------------------------------------------------------------
__global__ __launch_bounds__(256) void k_agg1(const unsigned short* __restrict__ h, // [N,64]
                                              const float* __restrict__ asrc,       // [N]
                                              const float* __restrict__ adst,       // [N]
                                              const int* __restrict__ rowptr,       // padded starts
                                              const int* __restrict__ degv,
                                              const int* __restrict__ col,
                                              const float* __restrict__ bias,       // [64]
                                              unsigned short* __restrict__ out) {   // [N,64]
    int n = blockIdx.x * 4 + (threadIdx.x >> 6);
    if (n >= N_NODES) return;
    int l = threadIdx.x & 63;
    int start = rowptr[n];
    int end   = start + degv[n];
    float adn = adst[n];

    float ssum = 0.f, o = 0.f;
    float tA0, tA1, tA2, tA3, tB0, tB1, tB2, tB3;
    unsigned short qA0, qA1, qA2, qA3, qB0, qB1, qB2, qB3;
    int4 cA, cB;

#define GATH1(c, T0, T1, T2, T3, Q0, Q1, Q2, Q3)                              \
    T0 = asrc[(unsigned)(c).x];                                               \
    T1 = asrc[(unsigned)(c).y];                                               \
    T2 = asrc[(unsigned)(c).z];                                               \
    T3 = asrc[(unsigned)(c).w];                                               \
    Q0 = h[(((unsigned)(c).x) << 6) + (unsigned)l];                           \
    Q1 = h[(((unsigned)(c).y) << 6) + (unsigned)l];                           \
    Q2 = h[(((unsigned)(c).z) << 6) + (unsigned)l];                           \
    Q3 = h[(((unsigned)(c).w) << 6) + (unsigned)l];

#define ASLOT1(IDX, TT, QQ, rem)                                              \
    {                                                                         \
        float e = TT + adn;                                                   \
        e = fmaxf(e, 0.2f * e);                                               \
        float ex = __expf(e);                                                 \
        ex = ((IDX) < (rem)) ? ex : 0.f;                                      \
        ssum += ex;                                                           \
        o += ex * b2f(QQ);                                                    \
    }

    int k = start;
    cA = *(const int4*)(col + k);
    cB = *(const int4*)(col + k + 4);
    GATH1(cA, tA0, tA1, tA2, tA3, qA0, qA1, qA2, qA3);
    for (;;) {
        bool hasB = (k + 4 < end);
        if (hasB) {
            GATH1(cB, tB0, tB1, tB2, tB3, qB0, qB1, qB2, qB3);
            cA = *(const int4*)(col + k + 8);
        }
        {
            int rem = end - k;
            ASLOT1(0, tA0, qA0, rem);
            ASLOT1(1, tA1, qA1, rem);
            ASLOT1(2, tA2, qA2, rem);
            ASLOT1(3, tA3, qA3, rem);
        }
        k += 4;
        if (!hasB) break;
        bool hasA = (k + 4 < end);
        if (hasA) {
            GATH1(cA, tA0, tA1, tA2, tA3, qA0, qA1, qA2, qA3);
            cB = *(const int4*)(col + k + 8);
        }
        {
            int rem = end - k;
            ASLOT1(0, tB0, qB0, rem);
            ASLOT1(1, tB1, qB1, rem);
            ASLOT1(2, tB2, qB2, rem);
            ASLOT1(3, tB3, qB3, rem);
        }
        k += 4;
        if (!hasA) break;
    }
#undef GATH1
#undef ASLOT1

    float v = o / (ssum + 1e-16f) + bias[l];
    v = (v > 0.f) ? v : expm1f(v);   // ELU
    out[(size_t)n * 64 + l] = f2b(v);
}

// ---------------------------------------------------------------------------
// Classifier: out[N,10] = h[N,64](bf16) @ Wc[10,64]^T + bc, fp32 out.
// ---------------------------------------------------------------------------
__global__ __launch_bounds__(256) void k_classifier(const unsigned short* __restrict__ h,
                                                    const float* __restrict__ Wc,
                                                    const float* __restrict__ bc,
                                                    float* __restrict__ out) {
    __shared__ float sW[640];
    for (int i = threadIdx.x; i < 640; i += blockDim.x) sW[i] = Wc[i];
    __syncthreads();
    int idx = blockIdx.x * blockDim.x + threadIdx.x;
    if (idx >= N_NODES * 10) return;
    int n = idx / 10, d = idx - n * 10;
    const unsigned short* hr = h + (size_t)n * 64;
    const float* wr = sW + d * 64;
    float acc = 0.f;
#pragma unroll
    for (int c = 0; c < 64; ++c) acc += b2f(hr[c]) * wr[c];
    out[idx] = acc + bc[d];
}

// ---------------------------------------------------------------------------
extern "C" void kernel_launch(void* const* d_in, const int* in_sizes, int n_in,
                              void* d_out, int out_size, void* d_ws, size_t ws_size,
                              hipStream_t stream) {
    const float* x    = (const float*)d_in[0];
    const int*   eidx = (const int*)  d_in[1];
    const float* W1   = (const float*)d_in[2];
    const float* a1s  = (const float*)d_in[3];
    const float* a1d  = (const float*)d_in[4];
    const float* b1   = (const float*)d_in[5];
    const float* W2   = (const float*)d_in[6];
    const float* a2s  = (const float*)d_in[7];
    const float* a2d  = (const float*)d_in[8];
    const float* b2   = (const float*)d_in[9];
    const float* W3   = (const float*)d_in[10];
    const float* a3s  = (const float*)d_in[11];
    const float* a3d  = (const float*)d_in[12];
    const float* b3   = (const float*)d_in[13];
    const float* Wc   = (const float*)d_in[14];
    const float* bc   = (const float*)d_in[15];
    float* out = (float*)d_out;

    // Workspace layout
    float* asbuf = (float*)d_ws;                              // N*8 fp32
    float* adbuf = asbuf + (size_t)N_NODES * 8;               // N*8 fp32
    unsigned short* aggX = (unsigned short*)(adbuf + (size_t)N_NODES * 8); // N*1024
    unsigned short* h2  = aggX + (size_t)N_NODES * 1024;      // N*64
    unsigned short* x3  = h2  + (size_t)N_NODES * 64;         // N*64
    unsigned short* h3  = x3  + (size_t)N_NODES * 64;         // N*64
    unsigned short* x4  = h3  + (size_t)N_NODES * 64;         // N*64
    unsigned short* xb  = x4  + (size_t)N_NODES * 64;         // N*128 (bf16 x)
    unsigned short* W1b = xb  + (size_t)N_NODES * 128;        // 512*128
    unsigned short* W2b = W1b + 512 * 128;                    // 64*512
    unsigned short* W3b = W2b + 64 * 512;                     // 64*64
    float* U    = (float*)(W3b + 64 * 64);                    // 16*128 fp32
    int* ibase  = (int*)(U + 16 * 128);
    int* deg    = ibase;                                      // N (zeroed in k_prep)
    int* flag   = deg + N_NODES;                              // 1
    int* rowptr = flag + 1;                                   // N+1 (padded starts)
    int* cursor = rowptr + N_NODES + 1;                       // N
    int* bsum   = cursor + N_NODES;                           // 256
    int* boff   = bsum + 256;                                 // 256
    int* col    = boff + 256;                                 // COL_CAP

    dim3 blk(256);
    const int SCAN_BLOCKS = (N_NODES + 255) / 256;            // 196
    const int PREP_BLOCKS = (N_NODES * 128 / 8 + 255) / 256;  // 3125

    // Prep: casts + U + attention logits (independent of CSR)
    k_prep<<<PREP_BLOCKS, blk, 0, stream>>>(x, W1, W2, W3, a1s, a1d,
                                            xb, W1b, W2b, W3b, U, deg, flag);
    k_attn<<<N_NODES / 16, blk, 0, stream>>>(xb, U, asbuf, adbuf);

    // CSR build
    k_detect<<<32, blk, 0, stream>>>(eidx, flag);
    k_degree<<<(ETOT + 255) / 256, blk, 0, stream>>>(eidx, flag, deg);
    k_scan1<<<SCAN_BLOCKS, blk, 0, stream>>>(deg, rowptr, bsum);
    k_scan2<<<1, blk, 0, stream>>>(bsum, boff, rowptr, SCAN_BLOCKS);
    k_scan3<<<SCAN_BLOCKS, blk, 0, stream>>>(rowptr, boff, deg, cursor, col);
    k_scatter<<<(ETOT + 255) / 256, blk, 0, stream>>>(eidx, flag, cursor, col);

    int mblocks   = (N_NODES + 63) / 64;   // 782
    int nblocks   = N_NODES / 4;           // 12500 (exact)

    // Layer 1 agg (VALU + pk_fma, input space) -> aggX
    k_aggx<<<nblocks, blk, 0, stream>>>(xb, asbuf, adbuf, rowptr, deg, col, aggX);

    // Fused GEMM1+GEMM2 (v2: 64-row tiles, 8 waves, 1 barrier)
    k_gemm12<<<mblocks, dim3(512), 0, stream>>>(aggX, W1b, b1, W2b, a2s, a2d,
                                                h2, asbuf, adbuf);

    // Layer 2 agg: h2 -> x3
    k_agg1<<<nblocks, blk, 0, stream>>>(h2, asbuf, adbuf, rowptr, deg, col, b2, x3);

    // Layer 3: x3[N,64] -> h3[N,64] (+ attn coefs); agg -> x4
    k_gemm<<<dim3(1, mblocks), blk, 0, stream>>>(x3, W3b, h3,
                                                 a3s, a3d, asbuf, adbuf,
                                                 N_NODES, 64, 64);
    k_agg1<<<nblocks, blk, 0, stream>>>(h3, asbuf, adbuf, rowptr, deg, col, b3, x4);

    // Classifier
    k_classifier<<<(N_NODES * 10 + 255) / 256, blk, 0, stream>>>(x4, Wc, bc, out);
}